// Round 3
// baseline (516.847 us; speedup 1.0000x reference)
//
#include <hip/hip_runtime.h>

typedef unsigned short u16;
typedef __bf16 bf16x8 __attribute__((ext_vector_type(8)));
typedef float f32x4 __attribute__((ext_vector_type(4)));
typedef unsigned short u16x8 __attribute__((ext_vector_type(8)));
typedef unsigned short u16x4 __attribute__((ext_vector_type(4)));

#define MFMA16(A,B,C) __builtin_amdgcn_mfma_f32_16x16x32_bf16(A,B,C,0,0,0)

__device__ __forceinline__ float b2f(u16 h){ unsigned u = ((unsigned)h)<<16; return __builtin_bit_cast(float,u); }
__device__ __forceinline__ u16 f2b(float f){ unsigned u = __builtin_bit_cast(unsigned,f); u += 0x7fffu + ((u>>16)&1u); return (u16)(u>>16); }
__device__ __forceinline__ bf16x8 ldb8(const u16* p){ return __builtin_bit_cast(bf16x8, *(const u16x8*)p); }

// async global->LDS, 16B per lane; LDS dest = wave-uniform base + lane*16.
__device__ __forceinline__ void g2lds16(const u16* g, u16* l){
  __builtin_amdgcn_global_load_lds((const __attribute__((address_space(1))) void*)g,
                                   (__attribute__((address_space(3))) void*)l, 16, 0, 0);
}

#define BAR   __builtin_amdgcn_s_barrier()
#define LGKM0 do{ asm volatile("s_waitcnt lgkmcnt(0)" ::: "memory"); __builtin_amdgcn_sched_barrier(0); }while(0)
#define VMC4  asm volatile("s_waitcnt vmcnt(4)" ::: "memory")

// B=16, C=256, H=W=64, NH=8, DH=64, POS_C=4.  4096 px/batch.
// fp32 inputs/output; bf16 internal.  CB batches/chunk from ws_size.
// K extended 256->320: cols 256..259 = pos channels, 260..319 = 0, so the
// QKV GEMM absorbs the rank-4 pos correction and K is 5 x BK=64 tiles.
// Layouts: XT [p][320] bf16; Q,K [bl][h][p][d]; Vt [bl][h][d][p];
// Vtc [bl][h][d][pT] (pT = (p&63)*64 + (p>>6)); U [bl][h][p][d].

// ---------------------------------------------------------------------------
// Weight prep: WP[1536][320] (cols 256..259 = pos weights, 260..319 = 0),
// BIAS[1536], WoP[256][512] (bf16).
__global__ void k_prep_w(const float* __restrict__ Wq, const float* __restrict__ Wk,
                         const float* __restrict__ Wv, const float* __restrict__ bq,
                         const float* __restrict__ bk, const float* __restrict__ bv,
                         const float* __restrict__ Wo,
                         u16* __restrict__ WP, u16* __restrict__ BIAS,
                         u16* __restrict__ WoP){
  int r = blockIdx.x;                 // 0..1791
  int tid = threadIdx.x;
  if (r < 1536){
    int t = r >> 9, rm = r & 511;
    const float* src = (t==0 ? Wq : (t==1 ? Wk : Wv)) + (long)rm*260;
    WP[(long)r*320 + tid] = f2b(src[tid]);
    if (tid < 64) WP[(long)r*320 + 256 + tid] = (tid < 4) ? f2b(src[256 + tid]) : (u16)0;
    if (tid == 0){
      const float* bs = (t==0 ? bq : (t==1 ? bk : bv));
      BIAS[r] = f2b(bs[rm]);
    }
  } else {
    int co = r - 1536;
    WoP[(long)co*512 + tid]       = f2b(Wo[(long)co*512 + tid]);
    WoP[(long)co*512 + 256 + tid] = f2b(Wo[(long)co*512 + 256 + tid]);
  }
}

// Diagnostic: ws too small -> fill out with 100.0f.
__global__ void k_sentinel(float* __restrict__ out){
  long i = (long)blockIdx.x*256 + threadIdx.x;
  out[i] = 100.0f;
}

// ---------------------------------------------------------------------------
// x [gb][c][4096] fp32 -> XT [bl*4096+p][320] bf16 (transpose + convert).
// ct==0 blocks also write the pos tail: cols 256..259 = pos, 260..319 = 0.
__global__ __launch_bounds__(256) void k_cvtx(const float* __restrict__ x,
                                              const float* __restrict__ pos,
                                              u16* __restrict__ XT, int b0){
  __shared__ u16 tile[64*65];
  int bidx = blockIdx.x;
  int ct = bidx & 3, pt = (bidx>>2)&63, bl = bidx>>8;
  int c0 = ct*64, p0 = pt*64;
  int tid = threadIdx.x;
  const float* xb = x + (long)(b0+bl)*256*4096;
  #pragma unroll
  for (int it=0; it<16; ++it){
    int idx = it*256 + tid; int cc = idx>>6, px = idx&63;
    tile[cc*65 + px] = f2b(xb[(long)(c0+cc)*4096 + p0 + px]);
  }
  __syncthreads();
  u16* dst = XT + ((long)(bl*4096 + p0))*320 + c0;
  #pragma unroll
  for (int it=0; it<4; ++it){
    int idx = it*256 + tid; int pp = idx>>4, c4 = (idx&15)*4;
    u16x4 o;
    #pragma unroll
    for (int u=0;u<4;++u) o[u] = tile[(c4+u)*65 + pp];
    *(u16x4*)&dst[(long)pp*320 + c4] = o;
  }
  if (ct == 0){
    int px = tid>>2, cb = (tid&3)*16;
    u16* row = XT + ((long)(bl*4096 + p0 + px))*320 + 256 + cb;
    #pragma unroll
    for (int half=0; half<2; ++half){
      u16x8 o;
      #pragma unroll
      for (int u=0;u<8;++u){
        int c = cb + half*8 + u;
        o[u] = (c < 4) ? f2b(pos[(long)c*4096 + p0 + px]) : (u16)0;
      }
      *(u16x8*)&row[half*8] = o;
    }
  }
}

// ---------------------------------------------------------------------------
// QKV GEMM, 256x256-tile multi-phase schedule (T2-layout+T3+T4+T5):
// M=1536 (oc), N=CB*4096 (px), K=320.  BK=64 as two [ks][256][32] subtiles
// (contiguous 1KB per fragment sweep -> structural-min LDS banking, linear
// global_load_lds).  8 waves (2M x 4N), per-wave output 128x64.
// 4 phases per K-tile: {ds_read subtile || stage half(t+1) || bar ||
// lgkmcnt(0) || setprio(1) 16xMFMA setprio(0) || [vmcnt(4)] bar}.
// vmcnt(4) (never 0) at ends of phases 1,3 keeps 4 loads in flight across
// barriers: half staged at t.ph0/ph1 is consumed at (t+1).ph0 -> ~4 phases
// of MFMA hide the HBM latency.  LDS 128 KiB, 1 block/CU.
__global__ __launch_bounds__(512,2) void k_qkv(
    const u16* __restrict__ XT, const u16* __restrict__ WP,
    const u16* __restrict__ BIAS,
    u16* __restrict__ Qb, u16* __restrict__ Kb, u16* __restrict__ Vt, int nwg){
  __shared__ u16 sm[65536];          // 128 KiB: A 2buf x 2ks x [256][32] | B same at +32768
  int hw = blockIdx.x;
  int bidx = (hw & 7)*(nwg >> 3) + (hw >> 3);   // nwg % 8 == 0 (96*CB)
  int mt = bidx % 6; long nt = bidx / 6;
  int oc0 = mt*256;
  int bl = (int)(nt >> 4); int pl0 = ((int)nt & 15)*256;
  int tid = threadIdx.x;
  int wid = tid>>6, lane = tid&63, l16 = lane&15, qd = lane>>4;
  int wm = wid>>2, wn = wid&3;
  const u16* gA = WP + (long)oc0*320;
  const u16* gB = XT + ((long)nt*256)*320;

  f32x4 zf = {0.f,0.f,0.f,0.f};
  f32x4 acc[8][4];
  #pragma unroll
  for (int i=0;i<8;++i){
    #pragma unroll
    for (int j=0;j<4;++j) acc[i][j] = zf;
  }

  // stage one ks-half (16 KB = 2 x 8KB calls); g -> [row][k] rows 0..255.
  auto stage2 = [&](const u16* g, int ldsOff){
    g2lds16(g + (long)(wid*16 + (lane>>2))*320 + (lane&3)*8,       &sm[ldsOff + wid*512]);
    g2lds16(g + (long)(128 + wid*16 + (lane>>2))*320 + (lane&3)*8, &sm[ldsOff + 4096 + wid*512]);
  };
  auto aOff = [&](int buf,int ks){ return (buf*2+ks)*8192; };
  auto bOff = [&](int buf,int ks){ return 32768 + (buf*2+ks)*8192; };

  bf16x8 rA[4], rB[4];
  auto ldA4 = [&](int buf,int ks,int mh){
    int base = aOff(buf,ks) + (wm*128 + mh*64 + l16)*32 + qd*8;
    #pragma unroll
    for (int i=0;i<4;++i) rA[i] = ldb8(&sm[base + i*16*32]);
  };
  auto ldB4 = [&](int buf,int ks){
    int base = bOff(buf,ks) + (wn*64 + l16)*32 + qd*8;
    #pragma unroll
    for (int i=0;i<4;++i) rB[i] = ldb8(&sm[base + i*16*32]);
  };
  auto mmac = [&](int mh){
    __builtin_amdgcn_s_setprio(1);
    #pragma unroll
    for (int i=0;i<4;++i){
      #pragma unroll
      for (int j=0;j<4;++j)
        acc[mh*4+i][j] = MFMA16(rA[i], rB[j], acc[mh*4+i][j]);
    }
    __builtin_amdgcn_s_setprio(0);
  };

  // prologue: tile0 all 4 halves -> buf0.  vmcnt(4) leaves ks1 halves in flight.
  stage2(gA + 0,  aOff(0,0));
  stage2(gB + 0,  bOff(0,0));
  stage2(gA + 32, aOff(0,1));
  stage2(gB + 32, bOff(0,1));
  VMC4; BAR;

  for (int t=0; t<5; ++t){
    int cur = t&1, nxt = cur^1;
    bool st = (t < 4);
    int k1 = (t+1)*64;
    // ph0: ks0, mi 0..3
    ldB4(cur,0); ldA4(cur,0,0);
    if (st) stage2(gA + k1, aOff(nxt,0));
    BAR; LGKM0; mmac(0); BAR;
    // ph1: ks0, mi 4..7
    ldA4(cur,0,1);
    if (st) stage2(gB + k1, bOff(nxt,0));
    BAR; LGKM0; mmac(1); VMC4; BAR;
    // ph2: ks1, mi 0..3
    ldB4(cur,1); ldA4(cur,1,0);
    if (st) stage2(gA + k1 + 32, aOff(nxt,1));
    BAR; LGKM0; mmac(0); BAR;
    // ph3: ks1, mi 4..7
    ldA4(cur,1,1);
    if (st) stage2(gB + k1 + 32, bOff(nxt,1));
    BAR; LGKM0; mmac(1); VMC4; BAR;
  }

  // ---- epilogue ----
  if (oc0 < 1024){
    // Q/K: direct u16x4 stores ([p][d], d-consecutive; L2 merges full lines).
    const u16* dstb = (oc0 < 512) ? Qb : Kb;
    #pragma unroll
    for (int mi=0;mi<8;++mi){
      int oc = oc0 + wm*128 + mi*16 + qd*4;
      int ocm = oc & 511;
      int hh = ocm>>6, dd = ocm&63;
      float bv4[4];
      #pragma unroll
      for (int r=0;r<4;++r) bv4[r] = b2f(BIAS[oc + r]);
      #pragma unroll
      for (int ni=0;ni<4;++ni){
        int pl = pl0 + wn*64 + ni*16 + l16;
        u16x4 pk;
        #pragma unroll
        for (int r=0;r<4;++r) pk[r] = f2b(acc[mi][ni][r] + bv4[r]);
        *(u16x4*)&((u16*)dstb)[((long)(bl*8+hh)*4096 + pl)*64 + dd] = pk;
      }
    }
  } else {
    // V: restage via LDS so Vt rows go out as 512B contiguous runs.
    // pass p: waves with wm==p write sT[px][136] (128 oc + 8 pad), all store.
    #pragma unroll
    for (int p=0;p<2;++p){
      if (wm == p){
        #pragma unroll
        for (int mi=0;mi<8;++mi){
          int ocl = mi*16 + qd*4;           // 0..124, +r
          float bv4[4];
          #pragma unroll
          for (int r=0;r<4;++r) bv4[r] = b2f(BIAS[oc0 + p*128 + ocl + r]);
          #pragma unroll
          for (int ni=0;ni<4;++ni){
            int px = wn*64 + ni*16 + l16;
            u16x4 pk;
            #pragma unroll
            for (int r=0;r<4;++r) pk[r] = f2b(acc[mi][ni][r] + bv4[r]);
            *(u16x4*)&sm[px*136 + ocl] = pk;
          }
        }
      }
      BAR;
      // cooperative store: 128 oc-rows x 32 chunks(8 px) = 4096 chunks.
      #pragma unroll
      for (int it=0; it<8; ++it){
        int c = it*512 + tid;
        int ocr = c>>5, px8 = (c&31)*8;
        u16x8 o;
        #pragma unroll
        for (int u=0;u<8;++u) o[u] = sm[(px8+u)*136 + ocr];
        int ocm = (oc0 & 511) + p*128 + ocr;
        int hh = ocm>>6, dd = ocm&63;
        *(u16x8*)&Vt[(long)(bl*8+hh)*262144 + (long)dd*4096 + pl0 + px8] = o;
      }
      BAR;
    }
  }
}

// ---------------------------------------------------------------------------
// Pixel-grid transpose: Vtc[ph][d][j*64+i] = Vt[ph][d][i*64+j].
__global__ __launch_bounds__(256) void k_vtr(const u16* __restrict__ Vt,
                                             u16* __restrict__ Vtc){
  __shared__ u16 tile[64*68];
  int bid = blockIdx.x;
  int d = bid & 63; long ph = bid >> 6;
  const u16* src = Vt + ph*262144 + (long)d*4096;
  u16* dst = Vtc + ph*262144 + (long)d*4096;
  int tid = threadIdx.x;
  #pragma unroll
  for (int it=0; it<2; ++it){
    int idx = it*256 + tid; int i = idx>>3, j8 = (idx&7)*8;
    u16x8 v = *(const u16x8*)&src[i*64 + j8];
    u16x4 lo = {v[0],v[1],v[2],v[3]}, hi = {v[4],v[5],v[6],v[7]};
    *(u16x4*)&tile[i*68 + j8]     = lo;
    *(u16x4*)&tile[i*68 + j8 + 4] = hi;
  }
  __syncthreads();
  #pragma unroll
  for (int it=0; it<2; ++it){
    int idx = it*256 + tid; int j = idx>>3, i8 = (idx&7)*8;
    u16x8 o;
    #pragma unroll
    for (int u=0;u<8;++u) o[u] = tile[(i8+u)*68 + j];
    *(u16x8*)&dst[j*64 + i8] = o;
  }
}

// ---------------------------------------------------------------------------
// Axial attention pass.  COL=0: rows (block (bl,h,i)), writes unnormalized
// U + fp32 m,l.  COL=1: cols (block (bl,h,j)), local stats in-register,
// flash-merges with row results, overwrites U with final A.
// V source pre-transposed (Vt for rows, Vtc for cols) -> pure vector staging.
// No XCD swizzle: blocks have zero inter-block reuse (T1 null-to-negative).
template<int COL>
__global__ __launch_bounds__(256) void k_attn(
    const u16* __restrict__ Qb, const u16* __restrict__ Kb,
    const u16* __restrict__ Vsrc, u16* __restrict__ U,
    float* __restrict__ M, float* __restrict__ L){
  __shared__ u16 sm[4*64*72];
  u16* Qs = sm;            // [line][d]  stride 72
  u16* Ks = sm + 4608;
  u16* VT = sm + 9216;     // [d][key]
  u16* Ps = sm + 13824;    // [q][k]
  int bid = blockIdx.x;
  int rc = bid&63, h=(bid>>6)&7, bl=bid>>9;
  long plane  = (long)(bl*8+h)*262144;
  long sbase  = (long)(bl*8+h)*4096;
  int tid = threadIdx.x;
  #pragma unroll
  for (int it=0; it<2; ++it){
    int idx = it*256 + tid; int row = idx>>3, c8 = (idx&7)*8;
    long gqk = plane + ((long)(COL ? (row*64 + rc) : (rc*64 + row)))*64 + c8;
    *(u16x8*)&Qs[row*72 + c8] = *(const u16x8*)&Qb[gqk];
    *(u16x8*)&Ks[row*72 + c8] = *(const u16x8*)&Kb[gqk];
    long gv = plane + (long)row*4096 + rc*64 + c8;   // row == d here
    *(u16x8*)&VT[row*72 + c8] = *(const u16x8*)&Vsrc[gv];
  }
  __syncthreads();
  int wid = tid>>6, lane = tid&63, l16 = lane&15, qd = lane>>4;
  int j0 = wid*16;
  f32x4 zf = {0.f,0.f,0.f,0.f};
  f32x4 sv[4] = {zf,zf,zf,zf};
  #pragma unroll
  for (int d0=0; d0<64; d0+=32){
    bf16x8 a = ldb8(&Qs[(j0+l16)*72 + d0 + qd*8]);
    #pragma unroll
    for (int n=0;n<4;++n){
      bf16x8 bb = ldb8(&Ks[(n*16+l16)*72 + d0 + qd*8]);
      sv[n] = MFMA16(a, bb, sv[n]);
    }
  }
  const float scale = 0.08838834764831845f;   // 1/sqrt(128)
  float mrow[4], lrow[4];
  #pragma unroll
  for (int r=0;r<4;++r){
    float mv = -1e30f;
    #pragma unroll
    for (int n=0;n<4;++n){ sv[n][r] *= scale; mv = fmaxf(mv, sv[n][r]); }
    mv = fmaxf(mv, __shfl_xor(mv,1)); mv = fmaxf(mv, __shfl_xor(mv,2));
    mv = fmaxf(mv, __shfl_xor(mv,4)); mv = fmaxf(mv, __shfl_xor(mv,8));
    float ls = 0.f;
    #pragma unroll
    for (int n=0;n<4;++n){ float p = expf(fminf(sv[n][r]-mv, 0.f)); sv[n][r] = p; ls += p; }
    ls += __shfl_xor(ls,1); ls += __shfl_xor(ls,2);
    ls += __shfl_xor(ls,4); ls += __shfl_xor(ls,8);
    mrow[r]=mv; lrow[r]=ls;
    int qi = j0 + qd*4 + r;
    #pragma unroll
    for (int n=0;n<4;++n) Ps[qi*72 + n*16 + l16] = f2b(sv[n][r]);
  }
  __syncthreads();
  f32x4 u4[4] = {zf,zf,zf,zf};
  #pragma unroll
  for (int k0=0;k0<64;k0+=32){
    bf16x8 a = ldb8(&Ps[(j0+l16)*72 + k0 + qd*8]);
    #pragma unroll
    for (int n=0;n<4;++n){
      bf16x8 bb = ldb8(&VT[(n*16+l16)*72 + k0 + qd*8]);
      u4[n] = MFMA16(a, bb, u4[n]);
    }
  }
  if (!COL){
    #pragma unroll
    for (int r=0;r<4;++r){
      int qi = j0 + qd*4 + r;
      long pl = (long)rc*64 + qi;
      long ob = (sbase + pl)*64;
      #pragma unroll
      for (int n=0;n<4;++n) U[ob + n*16 + l16] = f2b(u4[n][r]);
      if (l16==0){ M[sbase+pl]=mrow[r]; L[sbase+pl]=lrow[r]; }
    }
  } else {
    #pragma unroll
    for (int r=0;r<4;++r){
      int qi = j0 + qd*4 + r;
      long pix = sbase + (long)qi*64 + rc;
      float mw = M[pix], lw = L[pix];
      float mh = mrow[r], lh = lrow[r];
      float m  = fmaxf(mw, mh);
      float ew = expf(fminf(mw - m, 0.f));
      float eh = expf(fminf(mh - m, 0.f));
      float rden = 1.f / fmaxf(ew*lw + eh*lh, 1e-20f);
      long ob = pix*64;
      #pragma unroll
      for (int n=0;n<4;++n){
        float uw = b2f(U[ob + n*16 + l16]);
        U[ob + n*16 + l16] = f2b((ew*uw + eh*u4[n][r])*rden);
      }
    }
  }
}

// ---------------------------------------------------------------------------
// Output projection + residual: out = x + Wo @ A + bo.
// M=256 (co), N=CB*4096 (px), K=512.  A in U [bl][h][p][d] bf16.
// 2-phase dbuf + XCD swizzle (mt pairs share U panel).
__global__ __launch_bounds__(256) void k_oproj(
    const u16* __restrict__ WoP, const float* __restrict__ bo,
    const u16* __restrict__ AC, const float* __restrict__ x,
    float* __restrict__ out, int b0, int nwg){
  __shared__ u16 sW[2][128*32];
  __shared__ u16 sA[2][128*32];
  int hw = blockIdx.x;
  int bidx = (hw & 7)*(nwg >> 3) + (hw >> 3);   // nwg % 8 == 0 (64*CB)
  int mt = bidx & 1; long nt = bidx >> 1;
  int co0 = mt*128; long p0 = nt*128;
  int bl = (int)(p0>>12), pl0 = (int)(p0&4095);
  int gb = b0 + bl;
  int tid = threadIdx.x;
  int wid=tid>>6, lane=tid&63, l16=lane&15, qd=lane>>4;
  int wm=wid>>1, wn=wid&1;
  int srow = lane>>2, sc8 = (lane&3)*8;
  f32x4 zf = {0.f,0.f,0.f,0.f};
  f32x4 acc[4][4];
  #pragma unroll
  for (int i=0;i<4;++i){
    #pragma unroll
    for (int j=0;j<4;++j) acc[i][j] = zf;
  }
  auto stage = [&](int buf, int kk){
    #pragma unroll
    for (int c=0;c<2;++c){
      int seg = wid*2 + c;
      int row = seg*16 + srow;
      g2lds16(&WoP[(long)(co0+row)*512 + kk + sc8], &sW[buf][seg*512]);
      g2lds16(&AC[((long)(bl*8+(kk>>6))*4096 + pl0 + row)*64 + (kk&63) + sc8], &sA[buf][seg*512]);
    }
  };
  stage(0, 0);
  #pragma unroll
  for (int t=0; t<16; ++t){
    __syncthreads();
    if (t < 15) stage((t+1)&1, (t+1)*32);
    int cur = t&1;
    bf16x8 a[4], bb[4];
    #pragma unroll
    for (int mi=0;mi<4;++mi) a[mi]  = ldb8(&sW[cur][(wm*64+mi*16+l16)*32 + qd*8]);
    #pragma unroll
    for (int ni=0;ni<4;++ni) bb[ni] = ldb8(&sA[cur][(wn*64+ni*16+l16)*32 + qd*8]);
    #pragma unroll
    for (int mi=0;mi<4;++mi){
      #pragma unroll
      for (int ni=0;ni<4;++ni)
        acc[mi][ni] = MFMA16(a[mi], bb[ni], acc[mi][ni]);
    }
  }
  #pragma unroll
  for (int mi=0;mi<4;++mi){
    #pragma unroll
    for (int ni=0;ni<4;++ni){
      int n = wn*64+ni*16+l16; int pl = pl0+n;
      #pragma unroll
      for (int r=0;r<4;++r){
        int co = co0 + wm*64+mi*16+qd*4+r;
        long addr = ((long)(gb*256+co))*4096 + pl;
        out[addr] = acc[mi][ni][r] + bo[co] + x[addr];
      }
    }
  }
}

// ---------------------------------------------------------------------------
extern "C" void kernel_launch(void* const* d_in, const int* in_sizes, int n_in,
                              void* d_out, int out_size, void* d_ws, size_t ws_size,
                              hipStream_t stream) {
  (void)in_sizes; (void)n_in; (void)out_size;
  const float* x    = (const float*)d_in[0];
  const float* pos  = (const float*)d_in[1];
  const float* Wk   = (const float*)d_in[2];
  const float* bk   = (const float*)d_in[3];
  const float* Wq   = (const float*)d_in[4];
  const float* bq   = (const float*)d_in[5];
  const float* Wv   = (const float*)d_in[6];
  const float* bv   = (const float*)d_in[7];
  const float* Wo   = (const float*)d_in[8];
  const float* bo   = (const float*)d_in[9];
  float* out = (float*)d_out;
  char* ws = (char*)d_ws;

  // Fixed: WP 983,040 + BIAS 3,072 + WoP 262,144 = 1,248,256 B.
  // Per-batch: XT 2,621,440 + {Q,K,Vt,Vtc,U} 5 x 4,194,304 + {M,L} 2 x 131,072
  //          = 23,855,104 B.   (ws >= 273 MB proven -> CB = 8.)
  const long per_batch = 23855104l;
  const long fixed = 1248256l;
  if (fixed + per_batch > (long)ws_size){
    k_sentinel<<<65536, 256, 0, stream>>>(out);
    return;
  }
  int CB = 16;
  while (CB > 1 && fixed + (long)CB*per_batch > (long)ws_size) CB >>= 1;

  u16*  WP   = (u16*)(ws);
  u16*  BIAS = (u16*)(ws + 983040l);
  u16*  WoP  = (u16*)(ws + 986112l);
  long base  = fixed;
  u16*  XT   = (u16*)(ws + base);
  u16*  Qc   = (u16*)(ws + base + (long)CB*2621440l);
  u16*  Kc   = (u16*)((char*)Qc  + (long)CB*4194304l);
  u16*  Vt   = (u16*)((char*)Kc  + (long)CB*4194304l);
  u16*  Vtc  = (u16*)((char*)Vt  + (long)CB*4194304l);
  u16*  Uw   = (u16*)((char*)Vtc + (long)CB*4194304l);
  float* MWc = (float*)((char*)Uw + (long)CB*4194304l);
  float* LWc = (float*)((char*)MWc + (long)CB*131072l);

  k_prep_w<<<1792, 256, 0, stream>>>(Wq, Wk, Wv, bq, bk, bv, Wo, WP, BIAS, WoP);
  for (int b0 = 0; b0 < 16; b0 += CB){
    k_cvtx    <<<CB*256, 256, 0, stream>>>(x, pos, XT, b0);
    k_qkv     <<<CB*96,  512, 0, stream>>>(XT, WP, BIAS, Qc, Kc, Vt, CB*96);
    k_vtr     <<<CB*512, 256, 0, stream>>>(Vt, Vtc);
    k_attn<0> <<<CB*512, 256, 0, stream>>>(Qc, Kc, Vt,  Uw, MWc, LWc);
    k_attn<1> <<<CB*512, 256, 0, stream>>>(Qc, Kc, Vtc, Uw, MWc, LWc);
    k_oproj   <<<CB*64,  256, 0, stream>>>(WoP, bo, Uw, x, out, b0, CB*64);
  }
}

// Round 4
// 424.255 us; speedup vs baseline: 1.2182x; 1.2182x over previous
//
#include <hip/hip_runtime.h>

typedef unsigned short u16;
typedef __bf16 bf16x8 __attribute__((ext_vector_type(8)));
typedef float f32x4 __attribute__((ext_vector_type(4)));
typedef unsigned short u16x8 __attribute__((ext_vector_type(8)));
typedef unsigned short u16x4 __attribute__((ext_vector_type(4)));

#define MFMA16(A,B,C) __builtin_amdgcn_mfma_f32_16x16x32_bf16(A,B,C,0,0,0)

__device__ __forceinline__ float b2f(u16 h){ unsigned u = ((unsigned)h)<<16; return __builtin_bit_cast(float,u); }
__device__ __forceinline__ u16 f2b(float f){ unsigned u = __builtin_bit_cast(unsigned,f); u += 0x7fffu + ((u>>16)&1u); return (u16)(u>>16); }
__device__ __forceinline__ bf16x8 ldb8(const u16* p){ return __builtin_bit_cast(bf16x8, *(const u16x8*)p); }

// async global->LDS, 16B per lane; LDS dest = wave-uniform base + lane*16.
__device__ __forceinline__ void g2lds16(const u16* g, u16* l){
  __builtin_amdgcn_global_load_lds((const __attribute__((address_space(1))) void*)g,
                                   (__attribute__((address_space(3))) void*)l, 16, 0, 0);
}

#define BAR   __builtin_amdgcn_s_barrier()
#define LGKM0 do{ asm volatile("s_waitcnt lgkmcnt(0)" ::: "memory"); __builtin_amdgcn_sched_barrier(0); }while(0)
#define VMC4  asm volatile("s_waitcnt vmcnt(4)" ::: "memory")
#define VMC0  asm volatile("s_waitcnt vmcnt(0)" ::: "memory")

// B=16, C=256, H=W=64, NH=8, DH=64, POS_C=4.  4096 px/batch.
// fp32 inputs/output; bf16 internal.  CB batches/chunk from ws_size.
// K extended 256->320: cols 256..259 = pos channels, 260..319 = 0, so the
// QKV GEMM absorbs the rank-4 pos correction and K is 5 x BK=64 tiles.
// Layouts: XT [p][320] bf16; Q,K [bl][h][p][d]; Vt [bl][h][d][p];
// Vtc [bl][h][d][pT] (pT = (p&63)*64 + (p>>6)); U [bl][h][p][d].

// ---------------------------------------------------------------------------
// Weight prep: WP[1536][320] (cols 256..259 = pos weights, 260..319 = 0),
// BIAS[1536], WoP[256][512] (bf16).
__global__ void k_prep_w(const float* __restrict__ Wq, const float* __restrict__ Wk,
                         const float* __restrict__ Wv, const float* __restrict__ bq,
                         const float* __restrict__ bk, const float* __restrict__ bv,
                         const float* __restrict__ Wo,
                         u16* __restrict__ WP, u16* __restrict__ BIAS,
                         u16* __restrict__ WoP){
  int r = blockIdx.x;                 // 0..1791
  int tid = threadIdx.x;
  if (r < 1536){
    int t = r >> 9, rm = r & 511;
    const float* src = (t==0 ? Wq : (t==1 ? Wk : Wv)) + (long)rm*260;
    WP[(long)r*320 + tid] = f2b(src[tid]);
    if (tid < 64) WP[(long)r*320 + 256 + tid] = (tid < 4) ? f2b(src[256 + tid]) : (u16)0;
    if (tid == 0){
      const float* bs = (t==0 ? bq : (t==1 ? bk : bv));
      BIAS[r] = f2b(bs[rm]);
    }
  } else {
    int co = r - 1536;
    WoP[(long)co*512 + tid]       = f2b(Wo[(long)co*512 + tid]);
    WoP[(long)co*512 + 256 + tid] = f2b(Wo[(long)co*512 + 256 + tid]);
  }
}

// Diagnostic: ws too small -> fill out with 100.0f.
__global__ void k_sentinel(float* __restrict__ out){
  long i = (long)blockIdx.x*256 + threadIdx.x;
  out[i] = 100.0f;
}

// ---------------------------------------------------------------------------
// x [gb][c][4096] fp32 -> XT [bl*4096+p][320] bf16 (transpose + convert).
// ct==0 blocks also write the pos tail: cols 256..259 = pos, 260..319 = 0.
__global__ __launch_bounds__(256) void k_cvtx(const float* __restrict__ x,
                                              const float* __restrict__ pos,
                                              u16* __restrict__ XT, int b0){
  __shared__ u16 tile[64*65];
  int bidx = blockIdx.x;
  int ct = bidx & 3, pt = (bidx>>2)&63, bl = bidx>>8;
  int c0 = ct*64, p0 = pt*64;
  int tid = threadIdx.x;
  const float* xb = x + (long)(b0+bl)*256*4096;
  #pragma unroll
  for (int it=0; it<16; ++it){
    int idx = it*256 + tid; int cc = idx>>6, px = idx&63;
    tile[cc*65 + px] = f2b(xb[(long)(c0+cc)*4096 + p0 + px]);
  }
  __syncthreads();
  u16* dst = XT + ((long)(bl*4096 + p0))*320 + c0;
  #pragma unroll
  for (int it=0; it<4; ++it){
    int idx = it*256 + tid; int pp = idx>>4, c4 = (idx&15)*4;
    u16x4 o;
    #pragma unroll
    for (int u=0;u<4;++u) o[u] = tile[(c4+u)*65 + pp];
    *(u16x4*)&dst[(long)pp*320 + c4] = o;
  }
  if (ct == 0){
    int px = tid>>2, cb = (tid&3)*16;
    u16* row = XT + ((long)(bl*4096 + p0 + px))*320 + 256 + cb;
    #pragma unroll
    for (int half=0; half<2; ++half){
      u16x8 o;
      #pragma unroll
      for (int u=0;u<8;++u){
        int c = cb + half*8 + u;
        o[u] = (c < 4) ? f2b(pos[(long)c*4096 + p0 + px]) : (u16)0;
      }
      *(u16x8*)&row[half*8] = o;
    }
  }
}

// ---------------------------------------------------------------------------
// QKV GEMM, 256x256-tile multi-phase schedule (T2+T3+T4+T5):
// M=1536 (oc), N=CB*4096 (px), K=320.  BK=64 as two [ks][256][32] subtiles.
// T2: 8-row XOR swizzle (byte ^= (row&7)<<4), applied BOTH sides per rule 21:
// linear g2lds dest + inverse-permuted per-lane GLOBAL source + swizzled
// ds_read address.  Quarter-wave chunk%8 slots are then perfectly balanced
// (was 8-way conflict -> 19.5M SQ_LDS_BANK_CONFLICT in R3).
// 8 waves (2M x 4N), per-wave output 128x64.  4 phases/K-tile, vmcnt(4)
// (never 0 until final tile) keeps 4 loads in flight across barriers.
__global__ __launch_bounds__(512,2) void k_qkv(
    const u16* __restrict__ XT, const u16* __restrict__ WP,
    const u16* __restrict__ BIAS,
    u16* __restrict__ Qb, u16* __restrict__ Kb, u16* __restrict__ Vt, int nwg){
  __shared__ u16 sm[65536];          // 128 KiB: A 2buf x 2ks x [256][32] | B same at +32768
  int hw = blockIdx.x;
  int bidx = (hw & 7)*(nwg >> 3) + (hw >> 3);   // nwg % 8 == 0 (96*CB)
  int mt = bidx % 6; long nt = bidx / 6;
  int oc0 = mt*256;
  int bl = (int)(nt >> 4); int pl0 = ((int)nt & 15)*256;
  int tid = threadIdx.x;
  int wid = tid>>6, lane = tid&63, l16 = lane&15, qd = lane>>4;
  int wm = wid>>2, wn = wid&3;
  const u16* gA = WP + (long)oc0*320;
  const u16* gB = XT + ((long)nt*256)*320;

  // source pre-swizzle: lane (= physical 16B chunk) fetches logical chunk
  // l = lane ^ ((b2^b4)|(b3<<1)|(b4<<2))  (involution of byte^=(row&7)<<4).
  int b2=(lane>>2)&1, b3=(lane>>3)&1, b4=(lane>>4)&1;
  int lanez = lane ^ ((b2^b4) | (b3<<1) | (b4<<2));
  int srowz = lanez>>2, scolz = (lanez&3)*8;

  f32x4 zf = {0.f,0.f,0.f,0.f};
  f32x4 acc[8][4];
  #pragma unroll
  for (int i=0;i<8;++i){
    #pragma unroll
    for (int j=0;j<4;++j) acc[i][j] = zf;
  }

  // stage one ks-half (16 KB = 2 x 8KB calls); rows (wid*16 +) 0..255.
  auto stage2 = [&](const u16* g, int ldsOff){
    g2lds16(g + (long)(wid*16 + srowz)*320 + scolz,        &sm[ldsOff + wid*512]);
    g2lds16(g + (long)(128 + wid*16 + srowz)*320 + scolz,  &sm[ldsOff + 4096 + wid*512]);
  };
  auto aOff = [&](int buf,int ks){ return (buf*2+ks)*8192; };
  auto bOff = [&](int buf,int ks){ return 32768 + (buf*2+ks)*8192; };
  // swizzled read: logical (row, qd) -> u16 index
  auto swz = [&](int row, int q){ int byt = (row*64 + q*16) ^ ((row&7)<<4); return byt>>1; };

  bf16x8 rA[4], rB[4];
  auto ldA4 = [&](int buf,int ks,int mh){
    int o = aOff(buf,ks);
    #pragma unroll
    for (int i=0;i<4;++i) rA[i] = ldb8(&sm[o + swz(wm*128 + mh*64 + i*16 + l16, qd)]);
  };
  auto ldB4 = [&](int buf,int ks){
    int o = bOff(buf,ks);
    #pragma unroll
    for (int i=0;i<4;++i) rB[i] = ldb8(&sm[o + swz(wn*64 + i*16 + l16, qd)]);
  };
  auto mmac = [&](int mh){
    __builtin_amdgcn_s_setprio(1);
    #pragma unroll
    for (int i=0;i<4;++i){
      #pragma unroll
      for (int j=0;j<4;++j)
        acc[mh*4+i][j] = MFMA16(rA[i], rB[j], acc[mh*4+i][j]);
    }
    __builtin_amdgcn_s_setprio(0);
  };

  // prologue: tile0 all 4 halves -> buf0.  vmcnt(4) leaves ks1 halves in flight.
  stage2(gA + 0,  aOff(0,0));
  stage2(gB + 0,  bOff(0,0));
  stage2(gA + 32, aOff(0,1));
  stage2(gB + 32, bOff(0,1));
  VMC4; BAR;

  for (int t=0; t<5; ++t){
    int cur = t&1, nxt = cur^1;
    bool st = (t < 4);
    int k1 = (t+1)*64;
    // ph0: ks0, mi 0..3
    ldB4(cur,0); ldA4(cur,0,0);
    if (st) stage2(gA + k1, aOff(nxt,0));
    BAR; LGKM0; mmac(0); BAR;
    // ph1: ks0, mi 4..7
    ldA4(cur,0,1);
    if (st) stage2(gB + k1, bOff(nxt,0));
    BAR; LGKM0; mmac(1);
    if (st) { VMC4; } else { VMC0; }   // final tile: ensure ks1-cur landed
    BAR;
    // ph2: ks1, mi 0..3
    ldB4(cur,1); ldA4(cur,1,0);
    if (st) stage2(gA + k1 + 32, aOff(nxt,1));
    BAR; LGKM0; mmac(0); BAR;
    // ph3: ks1, mi 4..7
    ldA4(cur,1,1);
    if (st) stage2(gB + k1 + 32, bOff(nxt,1));
    BAR; LGKM0; mmac(1);
    if (st) { VMC4; } else { VMC0; }
    BAR;
  }

  // ---- epilogue ----
  if (oc0 < 1024){
    // Q/K: direct u16x4 stores ([p][d], d-consecutive; L2 merges full lines).
    const u16* dstb = (oc0 < 512) ? Qb : Kb;
    #pragma unroll
    for (int mi=0;mi<8;++mi){
      int oc = oc0 + wm*128 + mi*16 + qd*4;
      int ocm = oc & 511;
      int hh = ocm>>6, dd = ocm&63;
      float bv4[4];
      #pragma unroll
      for (int r=0;r<4;++r) bv4[r] = b2f(BIAS[oc + r]);
      #pragma unroll
      for (int ni=0;ni<4;++ni){
        int pl = pl0 + wn*64 + ni*16 + l16;
        u16x4 pk;
        #pragma unroll
        for (int r=0;r<4;++r) pk[r] = f2b(acc[mi][ni][r] + bv4[r]);
        *(u16x4*)&((u16*)dstb)[((long)(bl*8+hh)*4096 + pl)*64 + dd] = pk;
      }
    }
  } else {
    // V: restage via LDS as sT[oc][px] stride 264 (scalar conflict-free
    // writes, u16x8 contiguous reads), Vt rows stored as 512B runs.
    #pragma unroll
    for (int p=0;p<2;++p){
      if (wm == p){
        #pragma unroll
        for (int mi=0;mi<8;++mi){
          int ocl = mi*16 + qd*4;           // 0..124, +r
          float bv4[4];
          #pragma unroll
          for (int r=0;r<4;++r) bv4[r] = b2f(BIAS[oc0 + p*128 + ocl + r]);
          #pragma unroll
          for (int ni=0;ni<4;++ni){
            int px = wn*64 + ni*16 + l16;
            #pragma unroll
            for (int r=0;r<4;++r) sm[(ocl+r)*264 + px] = f2b(acc[mi][ni][r] + bv4[r]);
          }
        }
      }
      BAR;
      // cooperative store: 128 oc-rows x 32 chunks(8 px) = 4096 chunks.
      #pragma unroll
      for (int it=0; it<8; ++it){
        int c = it*512 + tid;
        int ocr = c>>5, px8 = (c&31)*8;
        u16x8 o = *(const u16x8*)&sm[ocr*264 + px8];
        int ocm = (oc0 & 511) + p*128 + ocr;
        int hh = ocm>>6, dd = ocm&63;
        *(u16x8*)&Vt[(long)(bl*8+hh)*262144 + (long)dd*4096 + pl0 + px8] = o;
      }
      BAR;
    }
  }
}

// ---------------------------------------------------------------------------
// Pixel-grid transpose: Vtc[ph][d][j*64+i] = Vt[ph][d][i*64+j].
__global__ __launch_bounds__(256) void k_vtr(const u16* __restrict__ Vt,
                                             u16* __restrict__ Vtc){
  __shared__ u16 tile[64*68];
  int bid = blockIdx.x;
  int d = bid & 63; long ph = bid >> 6;
  const u16* src = Vt + ph*262144 + (long)d*4096;
  u16* dst = Vtc + ph*262144 + (long)d*4096;
  int tid = threadIdx.x;
  #pragma unroll
  for (int it=0; it<2; ++it){
    int idx = it*256 + tid; int i = idx>>3, j8 = (idx&7)*8;
    u16x8 v = *(const u16x8*)&src[i*64 + j8];
    u16x4 lo = {v[0],v[1],v[2],v[3]}, hi = {v[4],v[5],v[6],v[7]};
    *(u16x4*)&tile[i*68 + j8]     = lo;
    *(u16x4*)&tile[i*68 + j8 + 4] = hi;
  }
  __syncthreads();
  #pragma unroll
  for (int it=0; it<2; ++it){
    int idx = it*256 + tid; int j = idx>>3, i8 = (idx&7)*8;
    u16x8 o;
    #pragma unroll
    for (int u=0;u<8;++u) o[u] = tile[(i8+u)*68 + j];
    *(u16x8*)&dst[j*64 + i8] = o;
  }
}

// ---------------------------------------------------------------------------
// Axial attention pass.  COL=0: rows (block (bl,h,i)), writes unnormalized
// U + fp32 m,l.  COL=1: cols (block (bl,h,j)), local stats in-register,
// flash-merges with row results, overwrites U with final A.
// V source pre-transposed (Vt for rows, Vtc for cols) -> pure vector staging.
template<int COL>
__global__ __launch_bounds__(256) void k_attn(
    const u16* __restrict__ Qb, const u16* __restrict__ Kb,
    const u16* __restrict__ Vsrc, u16* __restrict__ U,
    float* __restrict__ M, float* __restrict__ L){
  __shared__ u16 sm[4*64*72];
  u16* Qs = sm;            // [line][d]  stride 72
  u16* Ks = sm + 4608;
  u16* VT = sm + 9216;     // [d][key]
  u16* Ps = sm + 13824;    // [q][k]
  int bid = blockIdx.x;
  int rc = bid&63, h=(bid>>6)&7, bl=bid>>9;
  long plane  = (long)(bl*8+h)*262144;
  long sbase  = (long)(bl*8+h)*4096;
  int tid = threadIdx.x;
  #pragma unroll
  for (int it=0; it<2; ++it){
    int idx = it*256 + tid; int row = idx>>3, c8 = (idx&7)*8;
    long gqk = plane + ((long)(COL ? (row*64 + rc) : (rc*64 + row)))*64 + c8;
    *(u16x8*)&Qs[row*72 + c8] = *(const u16x8*)&Qb[gqk];
    *(u16x8*)&Ks[row*72 + c8] = *(const u16x8*)&Kb[gqk];
    long gv = plane + (long)row*4096 + rc*64 + c8;   // row == d here
    *(u16x8*)&VT[row*72 + c8] = *(const u16x8*)&Vsrc[gv];
  }
  __syncthreads();
  int wid = tid>>6, lane = tid&63, l16 = lane&15, qd = lane>>4;
  int j0 = wid*16;
  f32x4 zf = {0.f,0.f,0.f,0.f};
  f32x4 sv[4] = {zf,zf,zf,zf};
  #pragma unroll
  for (int d0=0; d0<64; d0+=32){
    bf16x8 a = ldb8(&Qs[(j0+l16)*72 + d0 + qd*8]);
    #pragma unroll
    for (int n=0;n<4;++n){
      bf16x8 bb = ldb8(&Ks[(n*16+l16)*72 + d0 + qd*8]);
      sv[n] = MFMA16(a, bb, sv[n]);
    }
  }
  const float scale = 0.08838834764831845f;   // 1/sqrt(128)
  float mrow[4], lrow[4];
  #pragma unroll
  for (int r=0;r<4;++r){
    float mv = -1e30f;
    #pragma unroll
    for (int n=0;n<4;++n){ sv[n][r] *= scale; mv = fmaxf(mv, sv[n][r]); }
    mv = fmaxf(mv, __shfl_xor(mv,1)); mv = fmaxf(mv, __shfl_xor(mv,2));
    mv = fmaxf(mv, __shfl_xor(mv,4)); mv = fmaxf(mv, __shfl_xor(mv,8));
    float ls = 0.f;
    #pragma unroll
    for (int n=0;n<4;++n){ float p = expf(fminf(sv[n][r]-mv, 0.f)); sv[n][r] = p; ls += p; }
    ls += __shfl_xor(ls,1); ls += __shfl_xor(ls,2);
    ls += __shfl_xor(ls,4); ls += __shfl_xor(ls,8);
    mrow[r]=mv; lrow[r]=ls;
    int qi = j0 + qd*4 + r;
    #pragma unroll
    for (int n=0;n<4;++n) Ps[qi*72 + n*16 + l16] = f2b(sv[n][r]);
  }
  __syncthreads();
  f32x4 u4[4] = {zf,zf,zf,zf};
  #pragma unroll
  for (int k0=0;k0<64;k0+=32){
    bf16x8 a = ldb8(&Ps[(j0+l16)*72 + k0 + qd*8]);
    #pragma unroll
    for (int n=0;n<4;++n){
      bf16x8 bb = ldb8(&VT[(n*16+l16)*72 + k0 + qd*8]);
      u4[n] = MFMA16(a, bb, u4[n]);
    }
  }
  if (!COL){
    #pragma unroll
    for (int r=0;r<4;++r){
      int qi = j0 + qd*4 + r;
      long pl = (long)rc*64 + qi;
      long ob = (sbase + pl)*64;
      #pragma unroll
      for (int n=0;n<4;++n) U[ob + n*16 + l16] = f2b(u4[n][r]);
      if (l16==0){ M[sbase+pl]=mrow[r]; L[sbase+pl]=lrow[r]; }
    }
  } else {
    #pragma unroll
    for (int r=0;r<4;++r){
      int qi = j0 + qd*4 + r;
      long pix = sbase + (long)qi*64 + rc;
      float mw = M[pix], lw = L[pix];
      float mh = mrow[r], lh = lrow[r];
      float m  = fmaxf(mw, mh);
      float ew = expf(fminf(mw - m, 0.f));
      float eh = expf(fminf(mh - m, 0.f));
      float rden = 1.f / fmaxf(ew*lw + eh*lh, 1e-20f);
      long ob = pix*64;
      #pragma unroll
      for (int n=0;n<4;++n){
        float uw = b2f(U[ob + n*16 + l16]);
        U[ob + n*16 + l16] = f2b((ew*uw + eh*u4[n][r])*rden);
      }
    }
  }
}

// ---------------------------------------------------------------------------
// Output projection + residual (round-0 form: single-buffer, no swizzle):
// out = x + Wo @ A + bo.  M=256 (co), N=CB*4096 (px), K=512.
__global__ __launch_bounds__(256) void k_oproj(
    const u16* __restrict__ WoP, const float* __restrict__ bo,
    const u16* __restrict__ AC, const float* __restrict__ x,
    float* __restrict__ out, int b0){
  __shared__ u16 sW[128*32];
  __shared__ u16 sA[128*32];
  int bidx = blockIdx.x;
  int mt = bidx & 1; long nt = bidx >> 1;
  int co0 = mt*128; long p0 = nt*128;
  int bl = (int)(p0>>12), pl0 = (int)(p0&4095);
  int gb = b0 + bl;
  int tid = threadIdx.x;
  int wid=tid>>6, lane=tid&63, l16=lane&15, qd=lane>>4;
  int wm=wid>>1, wn=wid&1;
  int srow = lane>>2, sc8 = (lane&3)*8;
  f32x4 zf = {0.f,0.f,0.f,0.f};
  f32x4 acc[4][4];
  #pragma unroll
  for (int i=0;i<4;++i){
    #pragma unroll
    for (int j=0;j<4;++j) acc[i][j] = zf;
  }
  for (int kk=0; kk<512; kk+=32){
    __syncthreads();
    #pragma unroll
    for (int c=0;c<2;++c){
      int seg = wid*2 + c;
      int row = seg*16 + srow;
      g2lds16(&WoP[(long)(co0+row)*512 + kk + sc8], &sW[seg*512]);
      g2lds16(&AC[((long)(bl*8+(kk>>6))*4096 + pl0 + row)*64 + (kk&63) + sc8], &sA[seg*512]);
    }
    __syncthreads();
    bf16x8 a[4], bb[4];
    #pragma unroll
    for (int mi=0;mi<4;++mi) a[mi]  = ldb8(&sW[(wm*64+mi*16+l16)*32 + qd*8]);
    #pragma unroll
    for (int ni=0;ni<4;++ni) bb[ni] = ldb8(&sA[(wn*64+ni*16+l16)*32 + qd*8]);
    #pragma unroll
    for (int mi=0;mi<4;++mi){
      #pragma unroll
      for (int ni=0;ni<4;++ni)
        acc[mi][ni] = MFMA16(a[mi], bb[ni], acc[mi][ni]);
    }
  }
  #pragma unroll
  for (int mi=0;mi<4;++mi){
    #pragma unroll
    for (int ni=0;ni<4;++ni){
      int n = wn*64+ni*16+l16; int pl = pl0+n;
      #pragma unroll
      for (int r=0;r<4;++r){
        int co = co0 + wm*64+mi*16+qd*4+r;
        long addr = ((long)(gb*256+co))*4096 + pl;
        out[addr] = acc[mi][ni][r] + bo[co] + x[addr];
      }
    }
  }
}

// ---------------------------------------------------------------------------
extern "C" void kernel_launch(void* const* d_in, const int* in_sizes, int n_in,
                              void* d_out, int out_size, void* d_ws, size_t ws_size,
                              hipStream_t stream) {
  (void)in_sizes; (void)n_in; (void)out_size;
  const float* x    = (const float*)d_in[0];
  const float* pos  = (const float*)d_in[1];
  const float* Wk   = (const float*)d_in[2];
  const float* bk   = (const float*)d_in[3];
  const float* Wq   = (const float*)d_in[4];
  const float* bq   = (const float*)d_in[5];
  const float* Wv   = (const float*)d_in[6];
  const float* bv   = (const float*)d_in[7];
  const float* Wo   = (const float*)d_in[8];
  const float* bo   = (const float*)d_in[9];
  float* out = (float*)d_out;
  char* ws = (char*)d_ws;

  // Fixed: WP 983,040 + BIAS 3,072 + WoP 262,144 = 1,248,256 B.
  // Per-batch: XT 2,621,440 + {Q,K,Vt,Vtc,U} 5 x 4,194,304 + {M,L} 2 x 131,072
  //          = 23,855,104 B.   (ws >= 273 MB proven -> CB = 8.)
  const long per_batch = 23855104l;
  const long fixed = 1248256l;
  if (fixed + per_batch > (long)ws_size){
    k_sentinel<<<65536, 256, 0, stream>>>(out);
    return;
  }
  int CB = 16;
  while (CB > 1 && fixed + (long)CB*per_batch > (long)ws_size) CB >>= 1;

  u16*  WP   = (u16*)(ws);
  u16*  BIAS = (u16*)(ws + 983040l);
  u16*  WoP  = (u16*)(ws + 986112l);
  long base  = fixed;
  u16*  XT   = (u16*)(ws + base);
  u16*  Qc   = (u16*)(ws + base + (long)CB*2621440l);
  u16*  Kc   = (u16*)((char*)Qc  + (long)CB*4194304l);
  u16*  Vt   = (u16*)((char*)Kc  + (long)CB*4194304l);
  u16*  Vtc  = (u16*)((char*)Vt  + (long)CB*4194304l);
  u16*  Uw   = (u16*)((char*)Vtc + (long)CB*4194304l);
  float* MWc = (float*)((char*)Uw + (long)CB*4194304l);
  float* LWc = (float*)((char*)MWc + (long)CB*131072l);

  k_prep_w<<<1792, 256, 0, stream>>>(Wq, Wk, Wv, bq, bk, bv, Wo, WP, BIAS, WoP);
  for (int b0 = 0; b0 < 16; b0 += CB){
    k_cvtx    <<<CB*256, 256, 0, stream>>>(x, pos, XT, b0);
    k_qkv     <<<CB*96,  512, 0, stream>>>(XT, WP, BIAS, Qc, Kc, Vt, CB*96);
    k_vtr     <<<CB*512, 256, 0, stream>>>(Vt, Vtc);
    k_attn<0> <<<CB*512, 256, 0, stream>>>(Qc, Kc, Vt,  Uw, MWc, LWc);
    k_attn<1> <<<CB*512, 256, 0, stream>>>(Qc, Kc, Vtc, Uw, MWc, LWc);
    k_oproj   <<<CB*64,  256, 0, stream>>>(WoP, bo, Uw, x, out, b0);
  }
}

// Round 5
// 407.060 us; speedup vs baseline: 1.2697x; 1.0422x over previous
//
#include <hip/hip_runtime.h>

typedef unsigned short u16;
typedef __bf16 bf16x8 __attribute__((ext_vector_type(8)));
typedef float f32x4 __attribute__((ext_vector_type(4)));
typedef unsigned short u16x8 __attribute__((ext_vector_type(8)));
typedef unsigned short u16x4 __attribute__((ext_vector_type(4)));

#define MFMA16(A,B,C) __builtin_amdgcn_mfma_f32_16x16x32_bf16(A,B,C,0,0,0)

__device__ __forceinline__ float b2f(u16 h){ unsigned u = ((unsigned)h)<<16; return __builtin_bit_cast(float,u); }
__device__ __forceinline__ u16 f2b(float f){ unsigned u = __builtin_bit_cast(unsigned,f); u += 0x7fffu + ((u>>16)&1u); return (u16)(u>>16); }
__device__ __forceinline__ bf16x8 ldb8(const u16* p){ return __builtin_bit_cast(bf16x8, *(const u16x8*)p); }

// async global->LDS, 16B per lane; LDS dest = wave-uniform base + lane*16.
__device__ __forceinline__ void g2lds16(const u16* g, u16* l){
  __builtin_amdgcn_global_load_lds((const __attribute__((address_space(1))) void*)g,
                                   (__attribute__((address_space(3))) void*)l, 16, 0, 0);
}

#define BAR   __builtin_amdgcn_s_barrier()
#define VMC4  asm volatile("s_waitcnt vmcnt(4)" ::: "memory")
#define VMC0  asm volatile("s_waitcnt vmcnt(0)" ::: "memory")

// B=16, C=256, H=W=64, NH=8, DH=64, POS_C=4.  4096 px/batch.
// fp32 inputs/output; bf16 internal.  CB batches/chunk from ws_size.
// K extended 256->320: cols 256..259 = pos channels, 260..319 = 0, so the
// QKV GEMM absorbs the rank-4 pos correction and K is 5 x BK=64 tiles.
// Layouts: XT [p][320] bf16; Q,K,V ALL [bl][h][p][d]; U [bl][h][p][d].
// V^T is built per-plane-slice inside k_attn (V staging address == Q/K's),
// killing the old Vt[d][p] restage + the whole k_vtr/Vtc pass.

// ---------------------------------------------------------------------------
// Weight prep: WP[1536][320] (cols 256..259 = pos weights, 260..319 = 0),
// BIAS[1536], WoP[256][512] (bf16).
__global__ void k_prep_w(const float* __restrict__ Wq, const float* __restrict__ Wk,
                         const float* __restrict__ Wv, const float* __restrict__ bq,
                         const float* __restrict__ bk, const float* __restrict__ bv,
                         const float* __restrict__ Wo,
                         u16* __restrict__ WP, u16* __restrict__ BIAS,
                         u16* __restrict__ WoP){
  int r = blockIdx.x;                 // 0..1791
  int tid = threadIdx.x;
  if (r < 1536){
    int t = r >> 9, rm = r & 511;
    const float* src = (t==0 ? Wq : (t==1 ? Wk : Wv)) + (long)rm*260;
    WP[(long)r*320 + tid] = f2b(src[tid]);
    if (tid < 64) WP[(long)r*320 + 256 + tid] = (tid < 4) ? f2b(src[256 + tid]) : (u16)0;
    if (tid == 0){
      const float* bs = (t==0 ? bq : (t==1 ? bk : bv));
      BIAS[r] = f2b(bs[rm]);
    }
  } else {
    int co = r - 1536;
    WoP[(long)co*512 + tid]       = f2b(Wo[(long)co*512 + tid]);
    WoP[(long)co*512 + 256 + tid] = f2b(Wo[(long)co*512 + 256 + tid]);
  }
}

// Diagnostic: ws too small -> fill out with 100.0f.
__global__ void k_sentinel(float* __restrict__ out){
  long i = (long)blockIdx.x*256 + threadIdx.x;
  out[i] = 100.0f;
}

// ---------------------------------------------------------------------------
// x [gb][c][4096] fp32 -> XT [bl*4096+p][320] bf16 (transpose + convert).
// ct==0 blocks also write the pos tail: cols 256..259 = pos, 260..319 = 0.
__global__ __launch_bounds__(256) void k_cvtx(const float* __restrict__ x,
                                              const float* __restrict__ pos,
                                              u16* __restrict__ XT, int b0){
  __shared__ u16 tile[64*65];
  int bidx = blockIdx.x;
  int ct = bidx & 3, pt = (bidx>>2)&63, bl = bidx>>8;
  int c0 = ct*64, p0 = pt*64;
  int tid = threadIdx.x;
  const float* xb = x + (long)(b0+bl)*256*4096;
  #pragma unroll
  for (int it=0; it<16; ++it){
    int idx = it*256 + tid; int cc = idx>>6, px = idx&63;
    tile[cc*65 + px] = f2b(xb[(long)(c0+cc)*4096 + p0 + px]);
  }
  __syncthreads();
  u16* dst = XT + ((long)(bl*4096 + p0))*320 + c0;
  #pragma unroll
  for (int it=0; it<4; ++it){
    int idx = it*256 + tid; int pp = idx>>4, c4 = (idx&15)*4;
    u16x4 o;
    #pragma unroll
    for (int u=0;u<4;++u) o[u] = tile[(c4+u)*65 + pp];
    *(u16x4*)&dst[(long)pp*320 + c4] = o;
  }
  if (ct == 0){
    int px = tid>>2, cb = (tid&3)*16;
    u16* row = XT + ((long)(bl*4096 + p0 + px))*320 + 256 + cb;
    #pragma unroll
    for (int half=0; half<2; ++half){
      u16x8 o;
      #pragma unroll
      for (int u=0;u<8;++u){
        int c = cb + half*8 + u;
        o[u] = (c < 4) ? f2b(pos[(long)c*4096 + p0 + px]) : (u16)0;
      }
      *(u16x8*)&row[half*8] = o;
    }
  }
}

// ---------------------------------------------------------------------------
// QKV GEMM, 256x256-tile multi-phase schedule (T2+T3+T4+T5):
// M=1536 (oc), N=CB*4096 (px), K=320.  BK=64 as two [ks][256][32] subtiles,
// 8-row XOR swizzle both sides (R4: conflicts 19.5M->2.9M).  8 waves (2Mx4N),
// per-wave output 128x64.  4 phases/K-tile; vmcnt(4) (never 0 until final
// tile) keeps 4 loads in flight across barriers.
// R5 change: NO inline-asm lgkmcnt(0)+sched_barrier pin per phase -- the
// ds_reads are ordinary loads, the compiler emits fine-grained lgkm waits
// (m141: order-pinning regression).  Epilogue: Q,K,V all [p][d] u16x4.
__global__ __launch_bounds__(512) void k_qkv(
    const u16* __restrict__ XT, const u16* __restrict__ WP,
    const u16* __restrict__ BIAS,
    u16* __restrict__ Qb, u16* __restrict__ Kb, u16* __restrict__ Vb, int nwg){
  __shared__ u16 sm[65536];          // 128 KiB: A 2buf x 2ks x [256][32] | B same at +32768
  int hw = blockIdx.x;
  int bidx = (hw & 7)*(nwg >> 3) + (hw >> 3);   // nwg % 8 == 0 (96*CB)
  int mt = bidx % 6; long nt = bidx / 6;
  int oc0 = mt*256;
  int bl = (int)(nt >> 4); int pl0 = ((int)nt & 15)*256;
  int tid = threadIdx.x;
  int wid = tid>>6, lane = tid&63, l16 = lane&15, qd = lane>>4;
  int wm = wid>>2, wn = wid&3;
  const u16* gA = WP + (long)oc0*320;
  const u16* gB = XT + ((long)nt*256)*320;

  // source pre-swizzle: lane (= physical 16B chunk) fetches logical chunk
  // l = lane ^ ((b2^b4)|(b3<<1)|(b4<<2))  (involution of byte^=(row&7)<<4).
  int b2=(lane>>2)&1, b3=(lane>>3)&1, b4=(lane>>4)&1;
  int lanez = lane ^ ((b2^b4) | (b3<<1) | (b4<<2));
  int srowz = lanez>>2, scolz = (lanez&3)*8;

  f32x4 zf = {0.f,0.f,0.f,0.f};
  f32x4 acc[8][4];
  #pragma unroll
  for (int i=0;i<8;++i){
    #pragma unroll
    for (int j=0;j<4;++j) acc[i][j] = zf;
  }

  // stage one ks-half (16 KB = 2 x 8KB calls); rows (wid*16 +) 0..255.
  auto stage2 = [&](const u16* g, int ldsOff){
    g2lds16(g + (long)(wid*16 + srowz)*320 + scolz,        &sm[ldsOff + wid*512]);
    g2lds16(g + (long)(128 + wid*16 + srowz)*320 + scolz,  &sm[ldsOff + 4096 + wid*512]);
  };
  auto aOff = [&](int buf,int ks){ return (buf*2+ks)*8192; };
  auto bOff = [&](int buf,int ks){ return 32768 + (buf*2+ks)*8192; };
  // swizzled read: logical (row, qd) -> u16 index
  auto swz = [&](int row, int q){ int byt = (row*64 + q*16) ^ ((row&7)<<4); return byt>>1; };

  bf16x8 rA[4], rB[4];
  auto ldA4 = [&](int buf,int ks,int mh){
    int o = aOff(buf,ks);
    #pragma unroll
    for (int i=0;i<4;++i) rA[i] = ldb8(&sm[o + swz(wm*128 + mh*64 + i*16 + l16, qd)]);
  };
  auto ldB4 = [&](int buf,int ks){
    int o = bOff(buf,ks);
    #pragma unroll
    for (int i=0;i<4;++i) rB[i] = ldb8(&sm[o + swz(wn*64 + i*16 + l16, qd)]);
  };
  auto mmac = [&](int mh){
    __builtin_amdgcn_s_setprio(1);
    #pragma unroll
    for (int i=0;i<4;++i){
      #pragma unroll
      for (int j=0;j<4;++j)
        acc[mh*4+i][j] = MFMA16(rA[i], rB[j], acc[mh*4+i][j]);
    }
    __builtin_amdgcn_s_setprio(0);
  };

  // prologue: tile0 all 4 halves -> buf0.  vmcnt(4) leaves ks1 halves in flight.
  stage2(gA + 0,  aOff(0,0));
  stage2(gB + 0,  bOff(0,0));
  stage2(gA + 32, aOff(0,1));
  stage2(gB + 32, bOff(0,1));
  VMC4; BAR;

  for (int t=0; t<5; ++t){
    int cur = t&1, nxt = cur^1;
    bool st = (t < 4);
    int k1 = (t+1)*64;
    // ph0: ks0, mi 0..3
    ldB4(cur,0); ldA4(cur,0,0);
    if (st) stage2(gA + k1, aOff(nxt,0));
    BAR; mmac(0); BAR;
    // ph1: ks0, mi 4..7
    ldA4(cur,0,1);
    if (st) stage2(gB + k1, bOff(nxt,0));
    BAR; mmac(1);
    if (st) { VMC4; } else { VMC0; }   // retire next-tile ks pair / final drain
    BAR;
    // ph2: ks1, mi 0..3
    ldB4(cur,1); ldA4(cur,1,0);
    if (st) stage2(gA + k1 + 32, aOff(nxt,1));
    BAR; mmac(0); BAR;
    // ph3: ks1, mi 4..7
    ldA4(cur,1,1);
    if (st) stage2(gB + k1 + 32, bOff(nxt,1));
    BAR; mmac(1);
    if (st) { VMC4; } else { VMC0; }
    BAR;
  }

  // ---- epilogue: Q, K, V all direct u16x4 [p][d] stores ----
  u16* dstb = (oc0 < 512) ? Qb : (oc0 < 1024 ? Kb : Vb);
  #pragma unroll
  for (int mi=0;mi<8;++mi){
    int oc = oc0 + wm*128 + mi*16 + qd*4;
    int ocm = oc & 511;
    int hh = ocm>>6, dd = ocm&63;
    float bv4[4];
    #pragma unroll
    for (int r=0;r<4;++r) bv4[r] = b2f(BIAS[oc + r]);
    #pragma unroll
    for (int ni=0;ni<4;++ni){
      int pl = pl0 + wn*64 + ni*16 + l16;
      u16x4 pk;
      #pragma unroll
      for (int r=0;r<4;++r) pk[r] = f2b(acc[mi][ni][r] + bv4[r]);
      *(u16x4*)&dstb[((long)(bl*8+hh)*4096 + pl)*64 + dd] = pk;
    }
  }
}

// ---------------------------------------------------------------------------
// Axial attention pass.  COL=0: rows (block (bl,h,i)), writes unnormalized
// U + fp32 m,l.  COL=1: cols (block (bl,h,j)), local stats in-register,
// flash-merges with row results, overwrites U with final A.
// V is [p][d] (same layout as Q/K): staged with the SAME gqk address and
// transposed into VT[d][k] via scalar writes.  VT k-XOR swizzle
// (k ^= ((d>>3)&7)<<3, both sides) keeps writes 8-banks-x-2-lanes free
// (plain stride-72 would be 16-way: d-step-8 * 144B == 0 mod 32 banks).
template<int COL>
__global__ __launch_bounds__(256) void k_attn(
    const u16* __restrict__ Qb, const u16* __restrict__ Kb,
    const u16* __restrict__ Vsrc, u16* __restrict__ U,
    float* __restrict__ M, float* __restrict__ L){
  __shared__ u16 sm[4*64*72];
  u16* Qs = sm;            // [line][d]  stride 72
  u16* Ks = sm + 4608;
  u16* VT = sm + 9216;     // [d][k^swz]
  u16* Ps = sm + 13824;    // [q][k]
  int bid = blockIdx.x;
  int rc = bid&63, h=(bid>>6)&7, bl=bid>>9;
  long plane  = (long)(bl*8+h)*262144;
  long sbase  = (long)(bl*8+h)*4096;
  int tid = threadIdx.x;
  #pragma unroll
  for (int it=0; it<2; ++it){
    int idx = it*256 + tid; int row = idx>>3, c8 = (idx&7)*8;
    long gqk = plane + ((long)(COL ? (row*64 + rc) : (rc*64 + row)))*64 + c8;
    *(u16x8*)&Qs[row*72 + c8] = *(const u16x8*)&Qb[gqk];
    *(u16x8*)&Ks[row*72 + c8] = *(const u16x8*)&Kb[gqk];
    u16x8 v = *(const u16x8*)&Vsrc[gqk];          // V[pix][d] -- same pattern
    int xr = row ^ ((idx&7)<<3);                  // (d>>3)&7 == idx&7 here
    #pragma unroll
    for (int u=0;u<8;++u) VT[(c8+u)*72 + xr] = v[u];
  }
  __syncthreads();
  int wid = tid>>6, lane = tid&63, l16 = lane&15, qd = lane>>4;
  int j0 = wid*16;
  f32x4 zf = {0.f,0.f,0.f,0.f};
  f32x4 sv[4] = {zf,zf,zf,zf};
  #pragma unroll
  for (int d0=0; d0<64; d0+=32){
    bf16x8 a = ldb8(&Qs[(j0+l16)*72 + d0 + qd*8]);
    #pragma unroll
    for (int n=0;n<4;++n){
      bf16x8 bb = ldb8(&Ks[(n*16+l16)*72 + d0 + qd*8]);
      sv[n] = MFMA16(a, bb, sv[n]);
    }
  }
  const float scale = 0.08838834764831845f;   // 1/sqrt(128)
  float mrow[4], lrow[4];
  #pragma unroll
  for (int r=0;r<4;++r){
    float mv = -1e30f;
    #pragma unroll
    for (int n=0;n<4;++n){ sv[n][r] *= scale; mv = fmaxf(mv, sv[n][r]); }
    mv = fmaxf(mv, __shfl_xor(mv,1)); mv = fmaxf(mv, __shfl_xor(mv,2));
    mv = fmaxf(mv, __shfl_xor(mv,4)); mv = fmaxf(mv, __shfl_xor(mv,8));
    float ls = 0.f;
    #pragma unroll
    for (int n=0;n<4;++n){ float p = expf(fminf(sv[n][r]-mv, 0.f)); sv[n][r] = p; ls += p; }
    ls += __shfl_xor(ls,1); ls += __shfl_xor(ls,2);
    ls += __shfl_xor(ls,4); ls += __shfl_xor(ls,8);
    mrow[r]=mv; lrow[r]=ls;
    int qi = j0 + qd*4 + r;
    #pragma unroll
    for (int n=0;n<4;++n) Ps[qi*72 + n*16 + l16] = f2b(sv[n][r]);
  }
  __syncthreads();
  f32x4 u4[4] = {zf,zf,zf,zf};
  #pragma unroll
  for (int k0=0;k0<64;k0+=32){
    bf16x8 a = ldb8(&Ps[(j0+l16)*72 + k0 + qd*8]);
    #pragma unroll
    for (int n=0;n<4;++n){
      int dd = n*16 + l16;
      bf16x8 bb = ldb8(&VT[dd*72 + ((k0 + qd*8) ^ (((dd>>3)&7)<<3))]);
      u4[n] = MFMA16(a, bb, u4[n]);
    }
  }
  if (!COL){
    #pragma unroll
    for (int r=0;r<4;++r){
      int qi = j0 + qd*4 + r;
      long pl = (long)rc*64 + qi;
      long ob = (sbase + pl)*64;
      #pragma unroll
      for (int n=0;n<4;++n) U[ob + n*16 + l16] = f2b(u4[n][r]);
      if (l16==0){ M[sbase+pl]=mrow[r]; L[sbase+pl]=lrow[r]; }
    }
  } else {
    #pragma unroll
    for (int r=0;r<4;++r){
      int qi = j0 + qd*4 + r;
      long pix = sbase + (long)qi*64 + rc;
      float mw = M[pix], lw = L[pix];
      float mh = mrow[r], lh = lrow[r];
      float m  = fmaxf(mw, mh);
      float ew = expf(fminf(mw - m, 0.f));
      float eh = expf(fminf(mh - m, 0.f));
      float rden = 1.f / fmaxf(ew*lw + eh*lh, 1e-20f);
      long ob = pix*64;
      #pragma unroll
      for (int n=0;n<4;++n){
        float uw = b2f(U[ob + n*16 + l16]);
        U[ob + n*16 + l16] = f2b((ew*uw + eh*u4[n][r])*rden);
      }
    }
  }
}

// ---------------------------------------------------------------------------
// Output projection + residual (round-0 form: single-buffer, no swizzle):
// out = x + Wo @ A + bo.  M=256 (co), N=CB*4096 (px), K=512.
__global__ __launch_bounds__(256) void k_oproj(
    const u16* __restrict__ WoP, const float* __restrict__ bo,
    const u16* __restrict__ AC, const float* __restrict__ x,
    float* __restrict__ out, int b0){
  __shared__ u16 sW[128*32];
  __shared__ u16 sA[128*32];
  int bidx = blockIdx.x;
  int mt = bidx & 1; long nt = bidx >> 1;
  int co0 = mt*128; long p0 = nt*128;
  int bl = (int)(p0>>12), pl0 = (int)(p0&4095);
  int gb = b0 + bl;
  int tid = threadIdx.x;
  int wid=tid>>6, lane=tid&63, l16=lane&15, qd=lane>>4;
  int wm=wid>>1, wn=wid&1;
  int srow = lane>>2, sc8 = (lane&3)*8;
  f32x4 zf = {0.f,0.f,0.f,0.f};
  f32x4 acc[4][4];
  #pragma unroll
  for (int i=0;i<4;++i){
    #pragma unroll
    for (int j=0;j<4;++j) acc[i][j] = zf;
  }
  for (int kk=0; kk<512; kk+=32){
    __syncthreads();
    #pragma unroll
    for (int c=0;c<2;++c){
      int seg = wid*2 + c;
      int row = seg*16 + srow;
      g2lds16(&WoP[(long)(co0+row)*512 + kk + sc8], &sW[seg*512]);
      g2lds16(&AC[((long)(bl*8+(kk>>6))*4096 + pl0 + row)*64 + (kk&63) + sc8], &sA[seg*512]);
    }
    __syncthreads();
    bf16x8 a[4], bb[4];
    #pragma unroll
    for (int mi=0;mi<4;++mi) a[mi]  = ldb8(&sW[(wm*64+mi*16+l16)*32 + qd*8]);
    #pragma unroll
    for (int ni=0;ni<4;++ni) bb[ni] = ldb8(&sA[(wn*64+ni*16+l16)*32 + qd*8]);
    #pragma unroll
    for (int mi=0;mi<4;++mi){
      #pragma unroll
      for (int ni=0;ni<4;++ni)
        acc[mi][ni] = MFMA16(a[mi], bb[ni], acc[mi][ni]);
    }
  }
  #pragma unroll
  for (int mi=0;mi<4;++mi){
    #pragma unroll
    for (int ni=0;ni<4;++ni){
      int n = wn*64+ni*16+l16; int pl = pl0+n;
      #pragma unroll
      for (int r=0;r<4;++r){
        int co = co0 + wm*64+mi*16+qd*4+r;
        long addr = ((long)(gb*256+co))*4096 + pl;
        out[addr] = acc[mi][ni][r] + bo[co] + x[addr];
      }
    }
  }
}

// ---------------------------------------------------------------------------
extern "C" void kernel_launch(void* const* d_in, const int* in_sizes, int n_in,
                              void* d_out, int out_size, void* d_ws, size_t ws_size,
                              hipStream_t stream) {
  (void)in_sizes; (void)n_in; (void)out_size;
  const float* x    = (const float*)d_in[0];
  const float* pos  = (const float*)d_in[1];
  const float* Wk   = (const float*)d_in[2];
  const float* bk   = (const float*)d_in[3];
  const float* Wq   = (const float*)d_in[4];
  const float* bq   = (const float*)d_in[5];
  const float* Wv   = (const float*)d_in[6];
  const float* bv   = (const float*)d_in[7];
  const float* Wo   = (const float*)d_in[8];
  const float* bo   = (const float*)d_in[9];
  float* out = (float*)d_out;
  char* ws = (char*)d_ws;

  // Fixed: WP 983,040 + BIAS 3,072 + WoP 262,144 = 1,248,256 B.
  // Per-batch: XT 2,621,440 + {Q,K,V,U} 4 x 4,194,304 + {M,L} 2 x 131,072
  //          = 19,660,800 B.   (ws >= 273 MB proven -> CB >= 8.)
  const long per_batch = 19660800l;
  const long fixed = 1248256l;
  if (fixed + per_batch > (long)ws_size){
    k_sentinel<<<65536, 256, 0, stream>>>(out);
    return;
  }
  int CB = 16;
  while (CB > 1 && fixed + (long)CB*per_batch > (long)ws_size) CB >>= 1;

  u16*  WP   = (u16*)(ws);
  u16*  BIAS = (u16*)(ws + 983040l);
  u16*  WoP  = (u16*)(ws + 986112l);
  long base  = fixed;
  u16*  XT   = (u16*)(ws + base);
  u16*  Qc   = (u16*)(ws + base + (long)CB*2621440l);
  u16*  Kc   = (u16*)((char*)Qc  + (long)CB*4194304l);
  u16*  Vc   = (u16*)((char*)Kc  + (long)CB*4194304l);
  u16*  Uw   = (u16*)((char*)Vc  + (long)CB*4194304l);
  float* MWc = (float*)((char*)Uw + (long)CB*4194304l);
  float* LWc = (float*)((char*)MWc + (long)CB*131072l);

  k_prep_w<<<1792, 256, 0, stream>>>(Wq, Wk, Wv, bq, bk, bv, Wo, WP, BIAS, WoP);
  for (int b0 = 0; b0 < 16; b0 += CB){
    k_cvtx    <<<CB*256, 256, 0, stream>>>(x, pos, XT, b0);
    k_qkv     <<<CB*96,  512, 0, stream>>>(XT, WP, BIAS, Qc, Kc, Vc, CB*96);
    k_attn<0> <<<CB*512, 256, 0, stream>>>(Qc, Kc, Vc, Uw, MWc, LWc);
    k_attn<1> <<<CB*512, 256, 0, stream>>>(Qc, Kc, Vc, Uw, MWc, LWc);
    k_oproj   <<<CB*64,  256, 0, stream>>>(WoP, bo, Uw, x, out, b0);
  }
}

// Round 6
// 403.290 us; speedup vs baseline: 1.2816x; 1.0093x over previous
//
#include <hip/hip_runtime.h>

typedef unsigned short u16;
typedef __bf16 bf16x8 __attribute__((ext_vector_type(8)));
typedef float f32x4 __attribute__((ext_vector_type(4)));
typedef unsigned short u16x8 __attribute__((ext_vector_type(8)));
typedef unsigned short u16x4 __attribute__((ext_vector_type(4)));

#define MFMA16(A,B,C) __builtin_amdgcn_mfma_f32_16x16x32_bf16(A,B,C,0,0,0)

__device__ __forceinline__ float b2f(u16 h){ unsigned u = ((unsigned)h)<<16; return __builtin_bit_cast(float,u); }
__device__ __forceinline__ u16 f2b(float f){ unsigned u = __builtin_bit_cast(unsigned,f); u += 0x7fffu + ((u>>16)&1u); return (u16)(u>>16); }
__device__ __forceinline__ bf16x8 ldb8(const u16* p){ return __builtin_bit_cast(bf16x8, *(const u16x8*)p); }

// async global->LDS, 16B per lane; LDS dest = wave-uniform base + lane*16.
__device__ __forceinline__ void g2lds16(const u16* g, u16* l){
  __builtin_amdgcn_global_load_lds((const __attribute__((address_space(1))) void*)g,
                                   (__attribute__((address_space(3))) void*)l, 16, 0, 0);
}

#define BAR   __builtin_amdgcn_s_barrier()
#define VMC4  asm volatile("s_waitcnt vmcnt(4)" ::: "memory")
#define VMC0  asm volatile("s_waitcnt vmcnt(0)" ::: "memory")

// B=16, C=256, H=W=64, NH=8, DH=64, POS_C=4.  4096 px/batch.
// fp32 inputs/output; bf16 internal.  CB batches/chunk from ws_size.
// K extended 256->320: cols 256..259 = pos channels, 260..319 = 0, so the
// QKV GEMM absorbs the rank-4 pos correction and K is 5 x BK=64 tiles.
// Layouts: XT [p][320] bf16; Q,K,V ALL [bl][h][p][d]; U [bl][h][p][d].
// V^T is built per-plane-slice inside k_attn (V staging address == Q/K's).

// ---------------------------------------------------------------------------
// Weight prep: WP[1536][320] (cols 256..259 = pos weights, 260..319 = 0),
// BIAS[1536], WoP[256][512] (bf16).
__global__ void k_prep_w(const float* __restrict__ Wq, const float* __restrict__ Wk,
                         const float* __restrict__ Wv, const float* __restrict__ bq,
                         const float* __restrict__ bk, const float* __restrict__ bv,
                         const float* __restrict__ Wo,
                         u16* __restrict__ WP, u16* __restrict__ BIAS,
                         u16* __restrict__ WoP){
  int r = blockIdx.x;                 // 0..1791
  int tid = threadIdx.x;
  if (r < 1536){
    int t = r >> 9, rm = r & 511;
    const float* src = (t==0 ? Wq : (t==1 ? Wk : Wv)) + (long)rm*260;
    WP[(long)r*320 + tid] = f2b(src[tid]);
    if (tid < 64) WP[(long)r*320 + 256 + tid] = (tid < 4) ? f2b(src[256 + tid]) : (u16)0;
    if (tid == 0){
      const float* bs = (t==0 ? bq : (t==1 ? bk : bv));
      BIAS[r] = f2b(bs[rm]);
    }
  } else {
    int co = r - 1536;
    WoP[(long)co*512 + tid]       = f2b(Wo[(long)co*512 + tid]);
    WoP[(long)co*512 + 256 + tid] = f2b(Wo[(long)co*512 + 256 + tid]);
  }
}

// Diagnostic: ws too small -> fill out with 100.0f.
__global__ void k_sentinel(float* __restrict__ out){
  long i = (long)blockIdx.x*256 + threadIdx.x;
  out[i] = 100.0f;
}

// ---------------------------------------------------------------------------
// x [gb][c][4096] fp32 -> XT [bl*4096+p][320] bf16 (transpose + convert).
// ct==0 blocks also write the pos tail: cols 256..259 = pos, 260..319 = 0.
__global__ __launch_bounds__(256) void k_cvtx(const float* __restrict__ x,
                                              const float* __restrict__ pos,
                                              u16* __restrict__ XT, int b0){
  __shared__ u16 tile[64*65];
  int bidx = blockIdx.x;
  int ct = bidx & 3, pt = (bidx>>2)&63, bl = bidx>>8;
  int c0 = ct*64, p0 = pt*64;
  int tid = threadIdx.x;
  const float* xb = x + (long)(b0+bl)*256*4096;
  #pragma unroll
  for (int it=0; it<16; ++it){
    int idx = it*256 + tid; int cc = idx>>6, px = idx&63;
    tile[cc*65 + px] = f2b(xb[(long)(c0+cc)*4096 + p0 + px]);
  }
  __syncthreads();
  u16* dst = XT + ((long)(bl*4096 + p0))*320 + c0;
  #pragma unroll
  for (int it=0; it<4; ++it){
    int idx = it*256 + tid; int pp = idx>>4, c4 = (idx&15)*4;
    u16x4 o;
    #pragma unroll
    for (int u=0;u<4;++u) o[u] = tile[(c4+u)*65 + pp];
    *(u16x4*)&dst[(long)pp*320 + c4] = o;
  }
  if (ct == 0){
    int px = tid>>2, cb = (tid&3)*16;
    u16* row = XT + ((long)(bl*4096 + p0 + px))*320 + 256 + cb;
    #pragma unroll
    for (int half=0; half<2; ++half){
      u16x8 o;
      #pragma unroll
      for (int u=0;u<8;++u){
        int c = cb + half*8 + u;
        o[u] = (c < 4) ? f2b(pos[(long)c*4096 + p0 + px]) : (u16)0;
      }
      *(u16x8*)&row[half*8] = o;
    }
  }
}

// ---------------------------------------------------------------------------
// QKV GEMM: M=1536 (oc), N=CB*4096 (px), K=320.  R6: 128x128 tile, BK=64
// (two [ks][128][32] subtiles), 4 waves (2Mx2N), 64 KiB LDS -> 2 blocks/CU.
// Rationale (R5 counters): thin-K output-dominated GEMM at 1 block/CU left
// every stage/vmcnt/epilogue-burst exposed (MfmaUtil 20% = floor/dur).  With
// 2 blocks/CU, one block's MFMA phases hide the other's prologue/epilogue.
// Schedule per K-tile (proven R4 skeleton): 2 phases {ds_read frags(cur) ||
// stage both ks-half subtiles(t+1) || BAR || 16 MFMA (setprio) || VMC4 ||
// BAR}.  vmcnt(4) after EVERY phase = the 4 loads issued one phase ago have
// landed; never 0 until the final tile.  8-row XOR swizzle both sides
// (R4-verified: conflicts 19.5M -> 2.9M).
__global__ __launch_bounds__(256) void k_qkv(
    const u16* __restrict__ XT, const u16* __restrict__ WP,
    const u16* __restrict__ BIAS,
    u16* __restrict__ Qb, u16* __restrict__ Kb, u16* __restrict__ Vb, int nwg){
  __shared__ u16 sm[32768];          // 64 KiB: A 2buf x 2ks x [128][32] | B same at +16384
  int hw = blockIdx.x;
  int bidx = (hw & 7)*(nwg >> 3) + (hw >> 3);   // nwg % 8 == 0 (384*CB)
  int mt = bidx % 12; long nt = bidx / 12;
  int oc0 = mt*128;
  int bl = (int)(nt >> 5); int pl0 = ((int)nt & 31)*128;
  int tid = threadIdx.x;
  int wid = tid>>6, lane = tid&63, l16 = lane&15, qd = lane>>4;
  int wm = wid>>1, wn = wid&1;
  const u16* gA = WP + (long)oc0*320;
  const u16* gB = XT + ((long)nt*128)*320;

  // source pre-swizzle: lane (= physical 16B chunk) fetches logical chunk
  // l = lane ^ ((b2^b4)|(b3<<1)|(b4<<2))  (involution of byte^=(row&7)<<4).
  int b2=(lane>>2)&1, b3=(lane>>3)&1, b4=(lane>>4)&1;
  int lanez = lane ^ ((b2^b4) | (b3<<1) | (b4<<2));
  int srowz = lanez>>2, scolz = (lanez&3)*8;

  f32x4 zf = {0.f,0.f,0.f,0.f};
  f32x4 acc[4][4];
  #pragma unroll
  for (int i=0;i<4;++i){
    #pragma unroll
    for (int j=0;j<4;++j) acc[i][j] = zf;
  }

  // stage one [128][32] subtile (8 KB = 2 x 4KB calls); 4 waves cover
  // rows 0..63 (call 1) and 64..127 (call 2).
  auto stage2 = [&](const u16* g, int ldsOff){
    g2lds16(g + (long)(wid*16 + srowz)*320 + scolz,       &sm[ldsOff + wid*512]);
    g2lds16(g + (long)(64 + wid*16 + srowz)*320 + scolz,  &sm[ldsOff + 2048 + wid*512]);
  };
  auto aOff = [&](int buf,int ks){ return (buf*2+ks)*4096; };
  auto bOff = [&](int buf,int ks){ return 16384 + (buf*2+ks)*4096; };
  // swizzled read: logical (row, qd) -> u16 index
  auto swz = [&](int row, int q){ int byt = (row*64 + q*16) ^ ((row&7)<<4); return byt>>1; };

  bf16x8 rA[4], rB[4];
  auto ldA4 = [&](int buf,int ks){
    int o = aOff(buf,ks);
    #pragma unroll
    for (int i=0;i<4;++i) rA[i] = ldb8(&sm[o + swz(wm*64 + i*16 + l16, qd)]);
  };
  auto ldB4 = [&](int buf,int ks){
    int o = bOff(buf,ks);
    #pragma unroll
    for (int i=0;i<4;++i) rB[i] = ldb8(&sm[o + swz(wn*64 + i*16 + l16, qd)]);
  };
  auto mmac = [&](){
    __builtin_amdgcn_s_setprio(1);
    #pragma unroll
    for (int i=0;i<4;++i){
      #pragma unroll
      for (int j=0;j<4;++j)
        acc[i][j] = MFMA16(rA[i], rB[j], acc[i][j]);
    }
    __builtin_amdgcn_s_setprio(0);
  };

  // prologue: tile0 all 4 subtiles -> buf0 (8 vm-ops/thread).
  // VMC4 -> A0,B0 (oldest 4) landed; A1,B1 still in flight.
  stage2(gA + 0,  aOff(0,0));
  stage2(gB + 0,  bOff(0,0));
  stage2(gA + 32, aOff(0,1));
  stage2(gB + 32, bOff(0,1));
  VMC4; BAR;

  for (int t=0; t<5; ++t){
    int cur = t&1, nxt = cur^1;
    bool st = (t < 4);
    int k1 = (t+1)*64;
    // ph0: ks0
    ldA4(cur,0); ldB4(cur,0);
    if (st){ stage2(gA + k1, aOff(nxt,0)); stage2(gB + k1, bOff(nxt,0)); }
    BAR; mmac();
    if (st) { VMC4; } else { VMC0; }   // drain prev-phase stages (final: A1,B1 cur)
    BAR;
    // ph1: ks1
    ldA4(cur,1); ldB4(cur,1);
    if (st){ stage2(gA + k1 + 32, aOff(nxt,1)); stage2(gB + k1 + 32, bOff(nxt,1)); }
    BAR; mmac();
    if (st) VMC4;                       // final tile: nothing outstanding
    BAR;
  }

  // ---- epilogue: Q, K, V direct u16x4 [p][d] stores ----
  u16* dstb = (oc0 < 512) ? Qb : (oc0 < 1024 ? Kb : Vb);
  #pragma unroll
  for (int mi=0;mi<4;++mi){
    int oc = oc0 + wm*64 + mi*16 + qd*4;
    int ocm = oc & 511;
    int hh = ocm>>6, dd = ocm&63;
    float bv4[4];
    #pragma unroll
    for (int r=0;r<4;++r) bv4[r] = b2f(BIAS[oc + r]);
    #pragma unroll
    for (int ni=0;ni<4;++ni){
      int pl = pl0 + wn*64 + ni*16 + l16;
      u16x4 pk;
      #pragma unroll
      for (int r=0;r<4;++r) pk[r] = f2b(acc[mi][ni][r] + bv4[r]);
      *(u16x4*)&dstb[((long)(bl*8+hh)*4096 + pl)*64 + dd] = pk;
    }
  }
}

// ---------------------------------------------------------------------------
// Axial attention pass.  COL=0: rows (block (bl,h,i)), writes unnormalized
// U + fp32 m,l.  COL=1: cols (block (bl,h,j)), local stats in-register,
// flash-merges with row results, overwrites U with final A.
// V is [p][d] (same layout as Q/K): staged with the SAME gqk address and
// transposed into VT[d][k] via scalar writes (k-XOR swizzle both sides).
template<int COL>
__global__ __launch_bounds__(256) void k_attn(
    const u16* __restrict__ Qb, const u16* __restrict__ Kb,
    const u16* __restrict__ Vsrc, u16* __restrict__ U,
    float* __restrict__ M, float* __restrict__ L){
  __shared__ u16 sm[4*64*72];
  u16* Qs = sm;            // [line][d]  stride 72
  u16* Ks = sm + 4608;
  u16* VT = sm + 9216;     // [d][k^swz]
  u16* Ps = sm + 13824;    // [q][k]
  int bid = blockIdx.x;
  int rc = bid&63, h=(bid>>6)&7, bl=bid>>9;
  long plane  = (long)(bl*8+h)*262144;
  long sbase  = (long)(bl*8+h)*4096;
  int tid = threadIdx.x;
  #pragma unroll
  for (int it=0; it<2; ++it){
    int idx = it*256 + tid; int row = idx>>3, c8 = (idx&7)*8;
    long gqk = plane + ((long)(COL ? (row*64 + rc) : (rc*64 + row)))*64 + c8;
    *(u16x8*)&Qs[row*72 + c8] = *(const u16x8*)&Qb[gqk];
    *(u16x8*)&Ks[row*72 + c8] = *(const u16x8*)&Kb[gqk];
    u16x8 v = *(const u16x8*)&Vsrc[gqk];          // V[pix][d] -- same pattern
    int xr = row ^ ((idx&7)<<3);                  // (d>>3)&7 == idx&7 here
    #pragma unroll
    for (int u=0;u<8;++u) VT[(c8+u)*72 + xr] = v[u];
  }
  __syncthreads();
  int wid = tid>>6, lane = tid&63, l16 = lane&15, qd = lane>>4;
  int j0 = wid*16;
  f32x4 zf = {0.f,0.f,0.f,0.f};
  f32x4 sv[4] = {zf,zf,zf,zf};
  #pragma unroll
  for (int d0=0; d0<64; d0+=32){
    bf16x8 a = ldb8(&Qs[(j0+l16)*72 + d0 + qd*8]);
    #pragma unroll
    for (int n=0;n<4;++n){
      bf16x8 bb = ldb8(&Ks[(n*16+l16)*72 + d0 + qd*8]);
      sv[n] = MFMA16(a, bb, sv[n]);
    }
  }
  const float scale = 0.08838834764831845f;   // 1/sqrt(128)
  float mrow[4], lrow[4];
  #pragma unroll
  for (int r=0;r<4;++r){
    float mv = -1e30f;
    #pragma unroll
    for (int n=0;n<4;++n){ sv[n][r] *= scale; mv = fmaxf(mv, sv[n][r]); }
    mv = fmaxf(mv, __shfl_xor(mv,1)); mv = fmaxf(mv, __shfl_xor(mv,2));
    mv = fmaxf(mv, __shfl_xor(mv,4)); mv = fmaxf(mv, __shfl_xor(mv,8));
    float ls = 0.f;
    #pragma unroll
    for (int n=0;n<4;++n){ float p = expf(fminf(sv[n][r]-mv, 0.f)); sv[n][r] = p; ls += p; }
    ls += __shfl_xor(ls,1); ls += __shfl_xor(ls,2);
    ls += __shfl_xor(ls,4); ls += __shfl_xor(ls,8);
    mrow[r]=mv; lrow[r]=ls;
    int qi = j0 + qd*4 + r;
    #pragma unroll
    for (int n=0;n<4;++n) Ps[qi*72 + n*16 + l16] = f2b(sv[n][r]);
  }
  __syncthreads();
  f32x4 u4[4] = {zf,zf,zf,zf};
  #pragma unroll
  for (int k0=0;k0<64;k0+=32){
    bf16x8 a = ldb8(&Ps[(j0+l16)*72 + k0 + qd*8]);
    #pragma unroll
    for (int n=0;n<4;++n){
      int dd = n*16 + l16;
      bf16x8 bb = ldb8(&VT[dd*72 + ((k0 + qd*8) ^ (((dd>>3)&7)<<3))]);
      u4[n] = MFMA16(a, bb, u4[n]);
    }
  }
  if (!COL){
    #pragma unroll
    for (int r=0;r<4;++r){
      int qi = j0 + qd*4 + r;
      long pl = (long)rc*64 + qi;
      long ob = (sbase + pl)*64;
      #pragma unroll
      for (int n=0;n<4;++n) U[ob + n*16 + l16] = f2b(u4[n][r]);
      if (l16==0){ M[sbase+pl]=mrow[r]; L[sbase+pl]=lrow[r]; }
    }
  } else {
    #pragma unroll
    for (int r=0;r<4;++r){
      int qi = j0 + qd*4 + r;
      long pix = sbase + (long)qi*64 + rc;
      float mw = M[pix], lw = L[pix];
      float mh = mrow[r], lh = lrow[r];
      float m  = fmaxf(mw, mh);
      float ew = expf(fminf(mw - m, 0.f));
      float eh = expf(fminf(mh - m, 0.f));
      float rden = 1.f / fmaxf(ew*lw + eh*lh, 1e-20f);
      long ob = pix*64;
      #pragma unroll
      for (int n=0;n<4;++n){
        float uw = b2f(U[ob + n*16 + l16]);
        U[ob + n*16 + l16] = f2b((ew*uw + eh*u4[n][r])*rden);
      }
    }
  }
}

// ---------------------------------------------------------------------------
// Output projection + residual (round-0 form: single-buffer, no swizzle):
// out = x + Wo @ A + bo.  M=256 (co), N=CB*4096 (px), K=512.
__global__ __launch_bounds__(256) void k_oproj(
    const u16* __restrict__ WoP, const float* __restrict__ bo,
    const u16* __restrict__ AC, const float* __restrict__ x,
    float* __restrict__ out, int b0){
  __shared__ u16 sW[128*32];
  __shared__ u16 sA[128*32];
  int bidx = blockIdx.x;
  int mt = bidx & 1; long nt = bidx >> 1;
  int co0 = mt*128; long p0 = nt*128;
  int bl = (int)(p0>>12), pl0 = (int)(p0&4095);
  int gb = b0 + bl;
  int tid = threadIdx.x;
  int wid=tid>>6, lane=tid&63, l16=lane&15, qd=lane>>4;
  int wm=wid>>1, wn=wid&1;
  int srow = lane>>2, sc8 = (lane&3)*8;
  f32x4 zf = {0.f,0.f,0.f,0.f};
  f32x4 acc[4][4];
  #pragma unroll
  for (int i=0;i<4;++i){
    #pragma unroll
    for (int j=0;j<4;++j) acc[i][j] = zf;
  }
  for (int kk=0; kk<512; kk+=32){
    __syncthreads();
    #pragma unroll
    for (int c=0;c<2;++c){
      int seg = wid*2 + c;
      int row = seg*16 + srow;
      g2lds16(&WoP[(long)(co0+row)*512 + kk + sc8], &sW[seg*512]);
      g2lds16(&AC[((long)(bl*8+(kk>>6))*4096 + pl0 + row)*64 + (kk&63) + sc8], &sA[seg*512]);
    }
    __syncthreads();
    bf16x8 a[4], bb[4];
    #pragma unroll
    for (int mi=0;mi<4;++mi) a[mi]  = ldb8(&sW[(wm*64+mi*16+l16)*32 + qd*8]);
    #pragma unroll
    for (int ni=0;ni<4;++ni) bb[ni] = ldb8(&sA[(wn*64+ni*16+l16)*32 + qd*8]);
    #pragma unroll
    for (int mi=0;mi<4;++mi){
      #pragma unroll
      for (int ni=0;ni<4;++ni)
        acc[mi][ni] = MFMA16(a[mi], bb[ni], acc[mi][ni]);
    }
  }
  #pragma unroll
  for (int mi=0;mi<4;++mi){
    #pragma unroll
    for (int ni=0;ni<4;++ni){
      int n = wn*64+ni*16+l16; int pl = pl0+n;
      #pragma unroll
      for (int r=0;r<4;++r){
        int co = co0 + wm*64+mi*16+qd*4+r;
        long addr = ((long)(gb*256+co))*4096 + pl;
        out[addr] = acc[mi][ni][r] + bo[co] + x[addr];
      }
    }
  }
}

// ---------------------------------------------------------------------------
extern "C" void kernel_launch(void* const* d_in, const int* in_sizes, int n_in,
                              void* d_out, int out_size, void* d_ws, size_t ws_size,
                              hipStream_t stream) {
  (void)in_sizes; (void)n_in; (void)out_size;
  const float* x    = (const float*)d_in[0];
  const float* pos  = (const float*)d_in[1];
  const float* Wk   = (const float*)d_in[2];
  const float* bk   = (const float*)d_in[3];
  const float* Wq   = (const float*)d_in[4];
  const float* bq   = (const float*)d_in[5];
  const float* Wv   = (const float*)d_in[6];
  const float* bv   = (const float*)d_in[7];
  const float* Wo   = (const float*)d_in[8];
  const float* bo   = (const float*)d_in[9];
  float* out = (float*)d_out;
  char* ws = (char*)d_ws;

  // Fixed: WP 983,040 + BIAS 3,072 + WoP 262,144 = 1,248,256 B.
  // Per-batch: XT 2,621,440 + {Q,K,V,U} 4 x 4,194,304 + {M,L} 2 x 131,072
  //          = 19,660,800 B.   (ws >= 273 MB proven -> CB >= 8.)
  const long per_batch = 19660800l;
  const long fixed = 1248256l;
  if (fixed + per_batch > (long)ws_size){
    k_sentinel<<<65536, 256, 0, stream>>>(out);
    return;
  }
  int CB = 16;
  while (CB > 1 && fixed + (long)CB*per_batch > (long)ws_size) CB >>= 1;

  u16*  WP   = (u16*)(ws);
  u16*  BIAS = (u16*)(ws + 983040l);
  u16*  WoP  = (u16*)(ws + 986112l);
  long base  = fixed;
  u16*  XT   = (u16*)(ws + base);
  u16*  Qc   = (u16*)(ws + base + (long)CB*2621440l);
  u16*  Kc   = (u16*)((char*)Qc  + (long)CB*4194304l);
  u16*  Vc   = (u16*)((char*)Kc  + (long)CB*4194304l);
  u16*  Uw   = (u16*)((char*)Vc  + (long)CB*4194304l);
  float* MWc = (float*)((char*)Uw + (long)CB*4194304l);
  float* LWc = (float*)((char*)MWc + (long)CB*131072l);

  k_prep_w<<<1792, 256, 0, stream>>>(Wq, Wk, Wv, bq, bk, bv, Wo, WP, BIAS, WoP);
  for (int b0 = 0; b0 < 16; b0 += CB){
    k_cvtx    <<<CB*256, 256, 0, stream>>>(x, pos, XT, b0);
    k_qkv     <<<CB*384, 256, 0, stream>>>(XT, WP, BIAS, Qc, Kc, Vc, CB*384);
    k_attn<0> <<<CB*512, 256, 0, stream>>>(Qc, Kc, Vc, Uw, MWc, LWc);
    k_attn<1> <<<CB*512, 256, 0, stream>>>(Qc, Kc, Vc, Uw, MWc, LWc);
    k_oproj   <<<CB*64,  256, 0, stream>>>(WoP, bo, Uw, x, out, b0);
  }
}